// Round 1
// baseline (1455.931 us; speedup 1.0000x reference)
//
#include <hip/hip_runtime.h>
#include <hip/hip_bf16.h>

#define LRELU(e) ((e) > 0.f ? (e) : 0.2f * (e))

// ---------------- CSR build ----------------

__global__ void k_count(const int* __restrict__ dstE, int E, int N, int* __restrict__ deg) {
    int i = blockIdx.x * blockDim.x + threadIdx.x;
    if (i < E) atomicAdd(&deg[dstE[i]], 1);
    else if (i < E + N) atomicAdd(&deg[i - E], 1);   // self loops
}

__global__ void k_scan(const int* __restrict__ deg, int N, int Etot,
                       int* __restrict__ rowptr, int* __restrict__ cursor) {
    __shared__ int wsum[16];
    __shared__ int carrysh;
    int t = threadIdx.x;
    if (t == 0) carrysh = 0;
    __syncthreads();
    int lane = t & 63, wid = t >> 6;
    for (int base = 0; base < N; base += 1024) {
        int v = (base + t < N) ? deg[base + t] : 0;
        int x = v;
        #pragma unroll
        for (int off = 1; off < 64; off <<= 1) {
            int y = __shfl_up(x, off, 64);
            if (lane >= off) x += y;
        }
        if (lane == 63) wsum[wid] = x;
        __syncthreads();
        if (wid == 0) {
            int s = (lane < 16) ? wsum[lane] : 0;
            #pragma unroll
            for (int off = 1; off < 16; off <<= 1) {
                int y = __shfl_up(s, off, 64);
                if (lane >= off) s += y;
            }
            if (lane < 16) wsum[lane] = s;
        }
        __syncthreads();
        int woff = (wid == 0) ? 0 : wsum[wid - 1];
        int incl = x + woff;
        int carry = carrysh;
        if (base + t < N) {
            int ex = carry + incl - v;
            rowptr[base + t] = ex;
            cursor[base + t] = ex;
        }
        __syncthreads();
        if (t == 1023) carrysh = carry + incl;
        __syncthreads();
    }
    if (t == 0) rowptr[N] = Etot;
}

__global__ void k_fill(const int* __restrict__ srcE, const int* __restrict__ dstE,
                       int E, int N, int* __restrict__ cursor, int* __restrict__ col) {
    int i = blockIdx.x * blockDim.x + threadIdx.x;
    if (i < E) {
        int d = dstE[i];
        int p = atomicAdd(&cursor[d], 1);
        col[p] = srcE[i];
    } else if (i < E + N) {
        int d = i - E;
        int p = atomicAdd(&cursor[d], 1);
        col[p] = d;
    }
}

// ---------------- GEMM: [N,128] @ [128,DOUT] ----------------
// Tile: 64 rows x DOUT cols, BK=64. fp32 vector ALU (no fp32 MFMA on CDNA4).

template <int DOUT>
__global__ __launch_bounds__(256) void k_gemm(const float* __restrict__ X,
                                              const float* __restrict__ W,
                                              float* __restrict__ Hout, int Nrows) {
    constexpr int CG  = DOUT / 4;   // col groups of 4
    constexpr int RPT = CG / 4;     // rows per thread (8 for 128, 4 for 64)
    constexpr int TY  = 256 / CG;   // row-group count
    __shared__ float Xs[64][65];    // [row][k], pad 65 -> conflict-free strided reads
    __shared__ float Ws[64][DOUT];

    const int tid = threadIdx.x;
    const int c4  = tid % CG;
    const int ty  = tid / CG;
    const int row0 = blockIdx.x * 64;

    float acc[RPT][4];
    #pragma unroll
    for (int r = 0; r < RPT; r++)
        #pragma unroll
        for (int c = 0; c < 4; c++) acc[r][c] = 0.f;

    for (int kt = 0; kt < 128; kt += 64) {
        // stage X tile (64 rows x 64 k)
        {
            int cx = tid & 15;       // float4 group within 64 k
            int rx = tid >> 4;       // 0..15
            #pragma unroll
            for (int p = 0; p < 4; p++) {
                int r = rx + p * 16;
                int grow = row0 + r;
                float4 v = make_float4(0.f, 0.f, 0.f, 0.f);
                if (grow < Nrows) v = *(const float4*)&X[(size_t)grow * 128 + kt + cx * 4];
                Xs[r][cx * 4 + 0] = v.x;
                Xs[r][cx * 4 + 1] = v.y;
                Xs[r][cx * 4 + 2] = v.z;
                Xs[r][cx * 4 + 3] = v.w;
            }
        }
        // stage W tile (64 k x DOUT)
        {
            int cw = tid % CG;
            int kr = tid / CG;
            #pragma unroll
            for (int p = 0; p < 64 / TY; p++) {
                int k = kr + p * TY;
                *(float4*)&Ws[k][cw * 4] = *(const float4*)&W[(size_t)(kt + k) * DOUT + cw * 4];
            }
        }
        __syncthreads();
        #pragma unroll 4
        for (int k = 0; k < 64; k++) {
            float4 w = *(const float4*)&Ws[k][c4 * 4];
            float xr[RPT];
            #pragma unroll
            for (int r = 0; r < RPT; r++) xr[r] = Xs[ty * RPT + r][k];
            #pragma unroll
            for (int r = 0; r < RPT; r++) {
                acc[r][0] += xr[r] * w.x;
                acc[r][1] += xr[r] * w.y;
                acc[r][2] += xr[r] * w.z;
                acc[r][3] += xr[r] * w.w;
            }
        }
        __syncthreads();
    }
    #pragma unroll
    for (int r = 0; r < RPT; r++) {
        int grow = row0 + ty * RPT + r;
        if (grow < Nrows) {
            float4 o = make_float4(acc[r][0], acc[r][1], acc[r][2], acc[r][3]);
            *(float4*)&Hout[(size_t)grow * DOUT + c4 * 4] = o;
        }
    }
}

// ---------------- attention logit coefficients (8 heads x 16) ----------------

__global__ void k_al(const float* __restrict__ H, const float* __restrict__ a_s,
                     const float* __restrict__ a_d, float* __restrict__ als,
                     float* __restrict__ ald, int N) {
    int i = blockIdx.x * blockDim.x + threadIdx.x;   // (node, head)
    if (i >= N * 8) return;
    int n = i >> 3, h = i & 7;
    const float4* hp = (const float4*)(H + (size_t)n * 128 + h * 16);
    const float4* sp = (const float4*)(a_s + h * 16);
    const float4* dp = (const float4*)(a_d + h * 16);
    float ss = 0.f, sd = 0.f;
    #pragma unroll
    for (int j = 0; j < 4; j++) {
        float4 hv = hp[j], sv = sp[j], dv = dp[j];
        ss += hv.x * sv.x + hv.y * sv.y + hv.z * sv.z + hv.w * sv.w;
        sd += hv.x * dv.x + hv.y * dv.y + hv.z * dv.z + hv.w * dv.w;
    }
    als[i] = ss;
    ald[i] = sd;
}

// ---------------- softmax + aggregate, 8 heads x 16 dims ----------------
// 128 threads per dst node (1 per output element), 2 nodes per block.

__global__ __launch_bounds__(256) void k_agg(const int* __restrict__ rowptr,
                                             const int* __restrict__ col,
                                             const float* __restrict__ H,
                                             const float* __restrict__ als,
                                             const float* __restrict__ ald,
                                             const float* __restrict__ bias,
                                             float* __restrict__ out, int N) {
    int node = blockIdx.x * 2 + (threadIdx.x >> 7);
    int lc = threadIdx.x & 127;      // h*16 + d
    int h = lc >> 4;
    if (node >= N) return;
    int beg = rowptr[node], end = rowptr[node + 1];
    float aldv = ald[node * 8 + h];
    float ssum = 0.f;
    for (int j = beg; j < end; j++) {
        int s = col[j];
        float e = als[s * 8 + h] + aldv;
        e = LRELU(e);
        ssum += __expf(e);
    }
    float inv = 1.f / (ssum + 1e-16f);
    float acc = 0.f;
    for (int j = beg; j < end; j++) {
        int s = col[j];
        float e = als[s * 8 + h] + aldv;
        e = LRELU(e);
        acc += __expf(e) * inv * H[(size_t)s * 128 + lc];
    }
    out[(size_t)node * 128 + lc] = acc + bias[lc];
}

// ---------------- BatchNorm stats (sum, sumsq per column) ----------------

__global__ void k_bnstats(const float* __restrict__ V, int N, float* __restrict__ sums) {
    int col = threadIdx.x & 127;
    int row0 = blockIdx.x * 2 + (threadIdx.x >> 7);
    int stride = gridDim.x * 2;
    float s = 0.f, q = 0.f;
    for (int n = row0; n < N; n += stride) {
        float v = V[(size_t)n * 128 + col];
        s += v;
        q += v * v;
    }
    atomicAdd(&sums[col], s);
    atomicAdd(&sums[128 + col], q);
}

// ---------------- BN apply + ReLU + residual ----------------

__global__ void k_bnapply(const float* __restrict__ V, const float* __restrict__ sums,
                          const float* __restrict__ g, const float* __restrict__ bt,
                          const float* __restrict__ xres, float* __restrict__ xout,
                          int N, float invN) {
    int i = blockIdx.x * blockDim.x + threadIdx.x;   // float4 index
    if (i >= N * 32) return;
    int c0 = (i & 31) * 4;
    float4 v = ((const float4*)V)[i];
    float4 xr = ((const float4*)xres)[i];
    float vv[4] = {v.x, v.y, v.z, v.w};
    float xx[4] = {xr.x, xr.y, xr.z, xr.w};
    float oo[4];
    #pragma unroll
    for (int j = 0; j < 4; j++) {
        int c = c0 + j;
        float mu = sums[c] * invN;
        float var = sums[128 + c] * invN - mu * mu;
        float y = (vv[j] - mu) * rsqrtf(var + 1e-5f) * g[c] + bt[c];
        oo[j] = fmaxf(y, 0.f) + xx[j];
    }
    ((float4*)xout)[i] = make_float4(oo[0], oo[1], oo[2], oo[3]);
}

// ---------------- layer-2 logits (1 head, 64 dims): one wave per node ----------------

__global__ void k_al2(const float* __restrict__ H2, const float* __restrict__ as2,
                      const float* __restrict__ ad2, float* __restrict__ als,
                      float* __restrict__ ald, int N) {
    int node = blockIdx.x * 4 + (threadIdx.x >> 6);
    int lc = threadIdx.x & 63;
    if (node >= N) return;
    float v = H2[(size_t)node * 64 + lc];
    float s = v * as2[lc];
    float d = v * ad2[lc];
    #pragma unroll
    for (int off = 32; off; off >>= 1) {
        s += __shfl_xor(s, off, 64);
        d += __shfl_xor(d, off, 64);
    }
    if (lc == 0) { als[node] = s; ald[node] = d; }
}

// ---------------- layer-2 aggregate + LayerNorm fused: one wave per node ----------------

__global__ void k_agg2ln(const int* __restrict__ rowptr, const int* __restrict__ col,
                         const float* __restrict__ H2, const float* __restrict__ als,
                         const float* __restrict__ ald, const float* __restrict__ b2,
                         const float* __restrict__ lng, const float* __restrict__ lnb,
                         float* __restrict__ out, int N) {
    int node = blockIdx.x * 4 + (threadIdx.x >> 6);
    int lc = threadIdx.x & 63;
    if (node >= N) return;
    int beg = rowptr[node], end = rowptr[node + 1];
    float aldv = ald[node];
    float ssum = 0.f;
    for (int j = beg; j < end; j++) {
        float e = als[col[j]] + aldv;
        e = LRELU(e);
        ssum += __expf(e);
    }
    float inv = 1.f / (ssum + 1e-16f);
    float acc = 0.f;
    for (int j = beg; j < end; j++) {
        int s = col[j];
        float e = als[s] + aldv;
        e = LRELU(e);
        acc += __expf(e) * inv * H2[(size_t)s * 64 + lc];
    }
    float v = acc + b2[lc];
    float su = v, sq = v * v;
    #pragma unroll
    for (int off = 32; off; off >>= 1) {
        su += __shfl_xor(su, off, 64);
        sq += __shfl_xor(sq, off, 64);
    }
    float mu = su * (1.f / 64.f);
    float var = sq * (1.f / 64.f) - mu * mu;
    float r = rsqrtf(var + 1e-5f);
    out[(size_t)node * 64 + lc] = (v - mu) * r * lng[lc] + lnb[lc];
}

// ---------------- launch ----------------

extern "C" void kernel_launch(void* const* d_in, const int* in_sizes, int n_in,
                              void* d_out, int out_size, void* d_ws, size_t ws_size,
                              hipStream_t stream) {
    const float* x   = (const float*)d_in[0];
    const int*   ei  = (const int*)d_in[1];
    const float* W0  = (const float*)d_in[2];
    const float* as0 = (const float*)d_in[3];
    const float* ad0 = (const float*)d_in[4];
    const float* b0  = (const float*)d_in[5];
    const float* g0  = (const float*)d_in[6];
    const float* bt0 = (const float*)d_in[7];
    const float* W1  = (const float*)d_in[8];
    const float* as1 = (const float*)d_in[9];
    const float* ad1 = (const float*)d_in[10];
    const float* b1  = (const float*)d_in[11];
    const float* g1  = (const float*)d_in[12];
    const float* bt1 = (const float*)d_in[13];
    const float* W2  = (const float*)d_in[14];
    const float* as2 = (const float*)d_in[15];
    const float* ad2 = (const float*)d_in[16];
    const float* b2  = (const float*)d_in[17];
    const float* lng = (const float*)d_in[18];
    const float* lnb = (const float*)d_in[19];

    const int N = in_sizes[0] / 128;
    const int E = in_sizes[1] / 2;
    const int Etot = E + N;

    char* p = (char*)d_ws;
    auto carve = [&](size_t bytes) {
        void* q = (void*)p;
        p += (bytes + 255) & ~(size_t)255;
        return q;
    };
    float* h      = (float*)carve((size_t)N * 128 * 4);
    float* agg    = (float*)carve((size_t)N * 128 * 4);
    float* x1     = (float*)carve((size_t)N * 128 * 4);
    float* als    = (float*)carve((size_t)N * 8 * 4);
    float* ald    = (float*)carve((size_t)N * 8 * 4);
    int*   rowptr = (int*)carve((size_t)(N + 1) * 4);
    int*   cursor = (int*)carve((size_t)(N + 1) * 4);
    int*   deg    = (int*)carve((size_t)N * 4);
    int*   col    = (int*)carve((size_t)Etot * 4);
    float* bns    = (float*)carve(256 * 4);

    const float invN = 1.f / (float)N;
    const int eb = (E + N + 255) / 256;

    // CSR build (dst-sorted, self loops appended)
    hipMemsetAsync(deg, 0, (size_t)N * 4, stream);
    k_count<<<eb, 256, 0, stream>>>(ei + E, E, N, deg);
    k_scan<<<1, 1024, 0, stream>>>(deg, N, Etot, rowptr, cursor);
    k_fill<<<eb, 256, 0, stream>>>(ei, ei + E, E, N, cursor, col);

    const int gb = (N + 63) / 64;

    // ---- layer 0 ----
    k_gemm<128><<<gb, 256, 0, stream>>>(x, W0, h, N);
    k_al<<<(N * 8 + 255) / 256, 256, 0, stream>>>(h, as0, ad0, als, ald, N);
    k_agg<<<(N + 1) / 2, 256, 0, stream>>>(rowptr, col, h, als, ald, b0, agg, N);
    hipMemsetAsync(bns, 0, 256 * 4, stream);
    k_bnstats<<<256, 256, 0, stream>>>(agg, N, bns);
    k_bnapply<<<(N * 32 + 255) / 256, 256, 0, stream>>>(agg, bns, g0, bt0, x, x1, N, invN);

    // ---- layer 1 ----
    k_gemm<128><<<gb, 256, 0, stream>>>(x1, W1, h, N);
    k_al<<<(N * 8 + 255) / 256, 256, 0, stream>>>(h, as1, ad1, als, ald, N);
    k_agg<<<(N + 1) / 2, 256, 0, stream>>>(rowptr, col, h, als, ald, b1, agg, N);
    hipMemsetAsync(bns, 0, 256 * 4, stream);
    k_bnstats<<<256, 256, 0, stream>>>(agg, N, bns);
    k_bnapply<<<(N * 32 + 255) / 256, 256, 0, stream>>>(agg, bns, g1, bt1, x1, x1, N, invN);

    // ---- layer 2 + LayerNorm ----
    k_gemm<64><<<gb, 256, 0, stream>>>(x1, W2, h, N);
    k_al2<<<(N + 3) / 4, 256, 0, stream>>>(h, as2, ad2, als, ald, N);
    k_agg2ln<<<(N + 3) / 4, 256, 0, stream>>>(rowptr, col, h, als, ald, b2, lng, lnb,
                                              (float*)d_out, N);
}

// Round 2
// 915.821 us; speedup vs baseline: 1.5898x; 1.5898x over previous
//
#include <hip/hip_runtime.h>
#include <hip/hip_bf16.h>

#define LRELU(e) ((e) > 0.f ? (e) : 0.2f * (e))

// ---------------- CSR build ----------------

__global__ void k_count(const int* __restrict__ dstE, int E, int N, int* __restrict__ deg) {
    int i = blockIdx.x * blockDim.x + threadIdx.x;
    if (i < E) atomicAdd(&deg[dstE[i]], 1);
    else if (i < E + N) atomicAdd(&deg[i - E], 1);   // self loops
}

__global__ void k_scan(const int* __restrict__ deg, int N, int Etot,
                       int* __restrict__ rowptr, int* __restrict__ cursor) {
    __shared__ int wsum[16];
    __shared__ int carrysh;
    int t = threadIdx.x;
    if (t == 0) carrysh = 0;
    __syncthreads();
    int lane = t & 63, wid = t >> 6;
    for (int base = 0; base < N; base += 1024) {
        int v = (base + t < N) ? deg[base + t] : 0;
        int x = v;
        #pragma unroll
        for (int off = 1; off < 64; off <<= 1) {
            int y = __shfl_up(x, off, 64);
            if (lane >= off) x += y;
        }
        if (lane == 63) wsum[wid] = x;
        __syncthreads();
        if (wid == 0) {
            int s = (lane < 16) ? wsum[lane] : 0;
            #pragma unroll
            for (int off = 1; off < 16; off <<= 1) {
                int y = __shfl_up(s, off, 64);
                if (lane >= off) s += y;
            }
            if (lane < 16) wsum[lane] = s;
        }
        __syncthreads();
        int woff = (wid == 0) ? 0 : wsum[wid - 1];
        int incl = x + woff;
        int carry = carrysh;
        if (base + t < N) {
            int ex = carry + incl - v;
            rowptr[base + t] = ex;
            cursor[base + t] = ex;
        }
        __syncthreads();
        if (t == 1023) carrysh = carry + incl;
        __syncthreads();
    }
    if (t == 0) rowptr[N] = Etot;
}

__global__ void k_fill(const int* __restrict__ srcE, const int* __restrict__ dstE,
                       int E, int N, int* __restrict__ cursor, int* __restrict__ col,
                       int* __restrict__ dstarr) {
    int i = blockIdx.x * blockDim.x + threadIdx.x;
    if (i < E) {
        int d = dstE[i];
        int p = atomicAdd(&cursor[d], 1);
        col[p] = srcE[i];
        dstarr[p] = d;
    } else if (i < E + N) {
        int d = i - E;
        int p = atomicAdd(&cursor[d], 1);
        col[p] = d;
        dstarr[p] = d;
    }
}

// ---------------- GEMM: [N,128] @ [128,DOUT] ----------------

template <int DOUT>
__global__ __launch_bounds__(256) void k_gemm(const float* __restrict__ X,
                                              const float* __restrict__ W,
                                              float* __restrict__ Hout, int Nrows) {
    constexpr int CG  = DOUT / 4;
    constexpr int RPT = CG / 4;
    constexpr int TY  = 256 / CG;
    __shared__ float Xs[64][65];
    __shared__ float Ws[64][DOUT];

    const int tid = threadIdx.x;
    const int c4  = tid % CG;
    const int ty  = tid / CG;
    const int row0 = blockIdx.x * 64;

    float acc[RPT][4];
    #pragma unroll
    for (int r = 0; r < RPT; r++)
        #pragma unroll
        for (int c = 0; c < 4; c++) acc[r][c] = 0.f;

    for (int kt = 0; kt < 128; kt += 64) {
        {
            int cx = tid & 15;
            int rx = tid >> 4;
            #pragma unroll
            for (int p = 0; p < 4; p++) {
                int r = rx + p * 16;
                int grow = row0 + r;
                float4 v = make_float4(0.f, 0.f, 0.f, 0.f);
                if (grow < Nrows) v = *(const float4*)&X[(size_t)grow * 128 + kt + cx * 4];
                Xs[r][cx * 4 + 0] = v.x;
                Xs[r][cx * 4 + 1] = v.y;
                Xs[r][cx * 4 + 2] = v.z;
                Xs[r][cx * 4 + 3] = v.w;
            }
        }
        {
            int cw = tid % CG;
            int kr = tid / CG;
            #pragma unroll
            for (int p = 0; p < 64 / TY; p++) {
                int k = kr + p * TY;
                *(float4*)&Ws[k][cw * 4] = *(const float4*)&W[(size_t)(kt + k) * DOUT + cw * 4];
            }
        }
        __syncthreads();
        #pragma unroll 4
        for (int k = 0; k < 64; k++) {
            float4 w = *(const float4*)&Ws[k][c4 * 4];
            float xr[RPT];
            #pragma unroll
            for (int r = 0; r < RPT; r++) xr[r] = Xs[ty * RPT + r][k];
            #pragma unroll
            for (int r = 0; r < RPT; r++) {
                acc[r][0] += xr[r] * w.x;
                acc[r][1] += xr[r] * w.y;
                acc[r][2] += xr[r] * w.z;
                acc[r][3] += xr[r] * w.w;
            }
        }
        __syncthreads();
    }
    #pragma unroll
    for (int r = 0; r < RPT; r++) {
        int grow = row0 + ty * RPT + r;
        if (grow < Nrows) {
            float4 o = make_float4(acc[r][0], acc[r][1], acc[r][2], acc[r][3]);
            *(float4*)&Hout[(size_t)grow * DOUT + c4 * 4] = o;
        }
    }
}

// ---------------- attention logit coefficients (8 heads x 16) ----------------

__global__ void k_al(const float* __restrict__ H, const float* __restrict__ a_s,
                     const float* __restrict__ a_d, float* __restrict__ als,
                     float* __restrict__ ald, int N) {
    int i = blockIdx.x * blockDim.x + threadIdx.x;
    if (i >= N * 8) return;
    int n = i >> 3, h = i & 7;
    const float4* hp = (const float4*)(H + (size_t)n * 128 + h * 16);
    const float4* sp = (const float4*)(a_s + h * 16);
    const float4* dp = (const float4*)(a_d + h * 16);
    float ss = 0.f, sd = 0.f;
    #pragma unroll
    for (int j = 0; j < 4; j++) {
        float4 hv = hp[j], sv = sp[j], dv = dp[j];
        ss += hv.x * sv.x + hv.y * sv.y + hv.z * sv.z + hv.w * sv.w;
        sd += hv.x * dv.x + hv.y * dv.y + hv.z * dv.z + hv.w * dv.w;
    }
    als[i] = ss;
    ald[i] = sd;
}

// ---------------- per-edge softmax weights (unnormalized), 8 heads ----------------

__global__ void k_edgew8(const int* __restrict__ col, const int* __restrict__ dstarr,
                         const float* __restrict__ als, const float* __restrict__ ald,
                         float* __restrict__ w, int Etot) {
    int i = blockIdx.x * blockDim.x + threadIdx.x;
    if (i >= Etot * 8) return;
    int j = i >> 3, h = i & 7;
    int s = col[j], d = dstarr[j];
    float e = als[s * 8 + h] + ald[d * 8 + h];
    e = LRELU(e);
    w[i] = __expf(e);
}

__global__ void k_edgew1(const int* __restrict__ col, const int* __restrict__ dstarr,
                         const float* __restrict__ als, const float* __restrict__ ald,
                         float* __restrict__ w, int Etot) {
    int j = blockIdx.x * blockDim.x + threadIdx.x;
    if (j >= Etot) return;
    float e = als[col[j]] + ald[dstarr[j]];
    e = LRELU(e);
    w[j] = __expf(e);
}

// ---------------- single-pass softmax-normalize + aggregate, 8 heads x 16 ----------------
// acc = sum_j w_j * H[src_j];  ssum = sum_j w_j;  out = acc/ssum + bias

__global__ __launch_bounds__(256) void k_agg(const int* __restrict__ rowptr,
                                             const int* __restrict__ col,
                                             const float* __restrict__ Hm,
                                             const float* __restrict__ w,
                                             const float* __restrict__ bias,
                                             float* __restrict__ out, int N) {
    int node = blockIdx.x * 2 + (threadIdx.x >> 7);
    int lc = threadIdx.x & 127;      // h*16 + d
    int h = lc >> 4;
    if (node >= N) return;
    int beg = rowptr[node], end = rowptr[node + 1];
    float ssum = 0.f, acc = 0.f;
    int j = beg;
    for (; j + 4 <= end; j += 4) {
        int c0 = col[j], c1 = col[j + 1], c2 = col[j + 2], c3 = col[j + 3];
        float w0 = w[j * 8 + h];
        float w1 = w[(j + 1) * 8 + h];
        float w2 = w[(j + 2) * 8 + h];
        float w3 = w[(j + 3) * 8 + h];
        float h0 = Hm[(size_t)c0 * 128 + lc];
        float h1 = Hm[(size_t)c1 * 128 + lc];
        float h2 = Hm[(size_t)c2 * 128 + lc];
        float h3 = Hm[(size_t)c3 * 128 + lc];
        ssum += (w0 + w1) + (w2 + w3);
        acc += w0 * h0;
        acc += w1 * h1;
        acc += w2 * h2;
        acc += w3 * h3;
    }
    for (; j < end; j++) {
        int s = col[j];
        float wv = w[j * 8 + h];
        ssum += wv;
        acc += wv * Hm[(size_t)s * 128 + lc];
    }
    out[(size_t)node * 128 + lc] = acc / (ssum + 1e-16f) + bias[lc];
}

// ---------------- BatchNorm stats ----------------

__global__ void k_bnstats(const float* __restrict__ V, int N, float* __restrict__ sums) {
    int col = threadIdx.x & 127;
    int row0 = blockIdx.x * 2 + (threadIdx.x >> 7);
    int stride = gridDim.x * 2;
    float s = 0.f, q = 0.f;
    for (int n = row0; n < N; n += stride) {
        float v = V[(size_t)n * 128 + col];
        s += v;
        q += v * v;
    }
    atomicAdd(&sums[col], s);
    atomicAdd(&sums[128 + col], q);
}

// ---------------- BN apply + ReLU + residual ----------------

__global__ void k_bnapply(const float* __restrict__ V, const float* __restrict__ sums,
                          const float* __restrict__ g, const float* __restrict__ bt,
                          const float* __restrict__ xres, float* __restrict__ xout,
                          int N, float invN) {
    int i = blockIdx.x * blockDim.x + threadIdx.x;
    if (i >= N * 32) return;
    int c0 = (i & 31) * 4;
    float4 v = ((const float4*)V)[i];
    float4 xr = ((const float4*)xres)[i];
    float vv[4] = {v.x, v.y, v.z, v.w};
    float xx[4] = {xr.x, xr.y, xr.z, xr.w};
    float oo[4];
    #pragma unroll
    for (int j = 0; j < 4; j++) {
        int c = c0 + j;
        float mu = sums[c] * invN;
        float var = sums[128 + c] * invN - mu * mu;
        float y = (vv[j] - mu) * rsqrtf(var + 1e-5f) * g[c] + bt[c];
        oo[j] = fmaxf(y, 0.f) + xx[j];
    }
    ((float4*)xout)[i] = make_float4(oo[0], oo[1], oo[2], oo[3]);
}

// ---------------- layer-2 logits (1 head, 64 dims) ----------------

__global__ void k_al2(const float* __restrict__ H2, const float* __restrict__ as2,
                      const float* __restrict__ ad2, float* __restrict__ als,
                      float* __restrict__ ald, int N) {
    int node = blockIdx.x * 4 + (threadIdx.x >> 6);
    int lc = threadIdx.x & 63;
    if (node >= N) return;
    float v = H2[(size_t)node * 64 + lc];
    float s = v * as2[lc];
    float d = v * ad2[lc];
    #pragma unroll
    for (int off = 32; off; off >>= 1) {
        s += __shfl_xor(s, off, 64);
        d += __shfl_xor(d, off, 64);
    }
    if (lc == 0) { als[node] = s; ald[node] = d; }
}

// ---------------- layer-2 single-pass aggregate + LayerNorm ----------------

__global__ void k_agg2ln(const int* __restrict__ rowptr, const int* __restrict__ col,
                         const float* __restrict__ H2, const float* __restrict__ w,
                         const float* __restrict__ b2,
                         const float* __restrict__ lng, const float* __restrict__ lnb,
                         float* __restrict__ out, int N) {
    int node = blockIdx.x * 4 + (threadIdx.x >> 6);
    int lc = threadIdx.x & 63;
    if (node >= N) return;
    int beg = rowptr[node], end = rowptr[node + 1];
    float ssum = 0.f, acc = 0.f;
    int j = beg;
    for (; j + 4 <= end; j += 4) {
        int c0 = col[j], c1 = col[j + 1], c2 = col[j + 2], c3 = col[j + 3];
        float w0 = w[j], w1 = w[j + 1], w2 = w[j + 2], w3 = w[j + 3];
        float h0 = H2[(size_t)c0 * 64 + lc];
        float h1 = H2[(size_t)c1 * 64 + lc];
        float h2 = H2[(size_t)c2 * 64 + lc];
        float h3 = H2[(size_t)c3 * 64 + lc];
        ssum += (w0 + w1) + (w2 + w3);
        acc += w0 * h0;
        acc += w1 * h1;
        acc += w2 * h2;
        acc += w3 * h3;
    }
    for (; j < end; j++) {
        int s = col[j];
        float wv = w[j];
        ssum += wv;
        acc += wv * H2[(size_t)s * 64 + lc];
    }
    float v = acc / (ssum + 1e-16f) + b2[lc];
    float su = v, sq = v * v;
    #pragma unroll
    for (int off = 32; off; off >>= 1) {
        su += __shfl_xor(su, off, 64);
        sq += __shfl_xor(sq, off, 64);
    }
    float mu = su * (1.f / 64.f);
    float var = sq * (1.f / 64.f) - mu * mu;
    float r = rsqrtf(var + 1e-5f);
    out[(size_t)node * 64 + lc] = (v - mu) * r * lng[lc] + lnb[lc];
}

// ---------------- launch ----------------

extern "C" void kernel_launch(void* const* d_in, const int* in_sizes, int n_in,
                              void* d_out, int out_size, void* d_ws, size_t ws_size,
                              hipStream_t stream) {
    const float* x   = (const float*)d_in[0];
    const int*   ei  = (const int*)d_in[1];
    const float* W0  = (const float*)d_in[2];
    const float* as0 = (const float*)d_in[3];
    const float* ad0 = (const float*)d_in[4];
    const float* b0  = (const float*)d_in[5];
    const float* g0  = (const float*)d_in[6];
    const float* bt0 = (const float*)d_in[7];
    const float* W1  = (const float*)d_in[8];
    const float* as1 = (const float*)d_in[9];
    const float* ad1 = (const float*)d_in[10];
    const float* b1  = (const float*)d_in[11];
    const float* g1  = (const float*)d_in[12];
    const float* bt1 = (const float*)d_in[13];
    const float* W2  = (const float*)d_in[14];
    const float* as2 = (const float*)d_in[15];
    const float* ad2 = (const float*)d_in[16];
    const float* b2  = (const float*)d_in[17];
    const float* lng = (const float*)d_in[18];
    const float* lnb = (const float*)d_in[19];

    const int N = in_sizes[0] / 128;
    const int E = in_sizes[1] / 2;
    const int Etot = E + N;

    char* p = (char*)d_ws;
    auto carve = [&](size_t bytes) {
        void* q = (void*)p;
        p += (bytes + 255) & ~(size_t)255;
        return q;
    };
    float* h      = (float*)carve((size_t)N * 128 * 4);
    float* agg    = (float*)carve((size_t)N * 128 * 4);
    float* x1     = (float*)carve((size_t)N * 128 * 4);
    float* als    = (float*)carve((size_t)N * 8 * 4);
    float* ald    = (float*)carve((size_t)N * 8 * 4);
    int*   rowptr = (int*)carve((size_t)(N + 1) * 4);
    int*   cursor = (int*)carve((size_t)(N + 1) * 4);
    int*   deg    = (int*)carve((size_t)N * 4);
    int*   col    = (int*)carve((size_t)Etot * 4);
    int*   dstarr = (int*)carve((size_t)Etot * 4);
    float* w      = (float*)carve((size_t)Etot * 8 * 4);
    float* bns    = (float*)carve(256 * 4);

    const float invN = 1.f / (float)N;
    const int eb = (E + N + 255) / 256;

    // CSR build (dst-sorted, self loops appended)
    hipMemsetAsync(deg, 0, (size_t)N * 4, stream);
    k_count<<<eb, 256, 0, stream>>>(ei + E, E, N, deg);
    k_scan<<<1, 1024, 0, stream>>>(deg, N, Etot, rowptr, cursor);
    k_fill<<<eb, 256, 0, stream>>>(ei, ei + E, E, N, cursor, col, dstarr);

    const int gb = (N + 63) / 64;
    const int ewb8 = (Etot * 8 + 255) / 256;
    const int ewb1 = (Etot + 255) / 256;

    // ---- layer 0 ----
    k_gemm<128><<<gb, 256, 0, stream>>>(x, W0, h, N);
    k_al<<<(N * 8 + 255) / 256, 256, 0, stream>>>(h, as0, ad0, als, ald, N);
    k_edgew8<<<ewb8, 256, 0, stream>>>(col, dstarr, als, ald, w, Etot);
    k_agg<<<(N + 1) / 2, 256, 0, stream>>>(rowptr, col, h, w, b0, agg, N);
    hipMemsetAsync(bns, 0, 256 * 4, stream);
    k_bnstats<<<256, 256, 0, stream>>>(agg, N, bns);
    k_bnapply<<<(N * 32 + 255) / 256, 256, 0, stream>>>(agg, bns, g0, bt0, x, x1, N, invN);

    // ---- layer 1 ----
    k_gemm<128><<<gb, 256, 0, stream>>>(x1, W1, h, N);
    k_al<<<(N * 8 + 255) / 256, 256, 0, stream>>>(h, as1, ad1, als, ald, N);
    k_edgew8<<<ewb8, 256, 0, stream>>>(col, dstarr, als, ald, w, Etot);
    k_agg<<<(N + 1) / 2, 256, 0, stream>>>(rowptr, col, h, w, b1, agg, N);
    hipMemsetAsync(bns, 0, 256 * 4, stream);
    k_bnstats<<<256, 256, 0, stream>>>(agg, N, bns);
    k_bnapply<<<(N * 32 + 255) / 256, 256, 0, stream>>>(agg, bns, g1, bt1, x1, x1, N, invN);

    // ---- layer 2 + LayerNorm ----
    k_gemm<64><<<gb, 256, 0, stream>>>(x1, W2, h, N);
    k_al2<<<(N + 3) / 4, 256, 0, stream>>>(h, as2, ad2, als, ald, N);
    k_edgew1<<<ewb1, 256, 0, stream>>>(col, dstarr, als, ald, w, Etot);
    k_agg2ln<<<(N + 3) / 4, 256, 0, stream>>>(rowptr, col, h, w, b2, lng, lnb,
                                              (float*)d_out, N);
}

// Round 3
// 763.403 us; speedup vs baseline: 1.9072x; 1.1997x over previous
//
#include <hip/hip_runtime.h>
#include <hip/hip_bf16.h>

#define LRELU(e) ((e) > 0.f ? (e) : 0.2f * (e))

typedef __attribute__((ext_vector_type(8))) short bf16x8;
typedef __attribute__((ext_vector_type(4))) float floatx4;

__device__ inline short f2bf(float f) {
    union { float f; unsigned u; } v; v.f = f;
    unsigned r = v.u + 0x7fffu + ((v.u >> 16) & 1u);
    return (short)(r >> 16);
}
__device__ inline float bflo(int p) {
    union { unsigned u; float f; } v; v.u = (unsigned)p << 16; return v.f;
}
__device__ inline float bfhi(int p) {
    union { unsigned u; float f; } v; v.u = (unsigned)p & 0xffff0000u; return v.f;
}
__device__ inline float bf2f(unsigned short s) {
    union { unsigned u; float f; } v; v.u = (unsigned)s << 16; return v.f;
}

// ---------------- CSR build ----------------

__global__ void k_count(const int* __restrict__ dstE, int E, int N, int* __restrict__ deg) {
    int i = blockIdx.x * blockDim.x + threadIdx.x;
    if (i < E) atomicAdd(&deg[dstE[i]], 1);
    else if (i < E + N) atomicAdd(&deg[i - E], 1);
}

__global__ void k_scan(const int* __restrict__ deg, int N, int Etot,
                       int* __restrict__ rowptr, int* __restrict__ cursor) {
    __shared__ int wsum[16];
    __shared__ int carrysh;
    int t = threadIdx.x;
    if (t == 0) carrysh = 0;
    __syncthreads();
    int lane = t & 63, wid = t >> 6;
    for (int base = 0; base < N; base += 1024) {
        int v = (base + t < N) ? deg[base + t] : 0;
        int x = v;
        #pragma unroll
        for (int off = 1; off < 64; off <<= 1) {
            int y = __shfl_up(x, off, 64);
            if (lane >= off) x += y;
        }
        if (lane == 63) wsum[wid] = x;
        __syncthreads();
        if (wid == 0) {
            int s = (lane < 16) ? wsum[lane] : 0;
            #pragma unroll
            for (int off = 1; off < 16; off <<= 1) {
                int y = __shfl_up(s, off, 64);
                if (lane >= off) s += y;
            }
            if (lane < 16) wsum[lane] = s;
        }
        __syncthreads();
        int woff = (wid == 0) ? 0 : wsum[wid - 1];
        int incl = x + woff;
        int carry = carrysh;
        if (base + t < N) {
            int ex = carry + incl - v;
            rowptr[base + t] = ex;
            cursor[base + t] = ex;
        }
        __syncthreads();
        if (t == 1023) carrysh = carry + incl;
        __syncthreads();
    }
    if (t == 0) rowptr[N] = Etot;
}

__global__ void k_fill(const int* __restrict__ srcE, const int* __restrict__ dstE,
                       int E, int N, int* __restrict__ cursor, int* __restrict__ col,
                       int* __restrict__ dstarr) {
    int i = blockIdx.x * blockDim.x + threadIdx.x;
    if (i < E) {
        int d = dstE[i];
        int p = atomicAdd(&cursor[d], 1);
        col[p] = srcE[i];
        dstarr[p] = d;
    } else if (i < E + N) {
        int d = i - E;
        int p = atomicAdd(&cursor[d], 1);
        col[p] = d;
        dstarr[p] = d;
    }
}

// ---------------- W prep: fp32 [128,DOUT] -> bf16 transposed [DOUT,128] ----------------

__global__ void k_wprep(const float* __restrict__ W, short* __restrict__ Wt, int DOUT) {
    int i = blockIdx.x * blockDim.x + threadIdx.x;
    if (i >= DOUT * 128) return;
    int n = i >> 7, k = i & 127;
    Wt[n * 128 + k] = f2bf(W[k * DOUT + n]);
}

// ---------------- MFMA bf16 GEMM: [N,128] @ [128,DOUT] -> bf16 Hout ----------------
// block: 256 threads (4 waves), tile 128 rows x DOUT cols, K=128 staged once.

template <int DOUT>
__global__ __launch_bounds__(256) void k_gemm(const float* __restrict__ X,
                                              const short* __restrict__ Wt,
                                              short* __restrict__ Hout, int Nrows) {
    constexpr int KP = 136;            // padded K stride (shorts): 272 B row
    constexpr int CT = DOUT / 16;      // col tiles
    __shared__ __align__(16) short Xs[128 * KP];
    __shared__ __align__(16) short Ws[DOUT * KP];

    const int tid = threadIdx.x;
    const int row0 = blockIdx.x * 128;

    // stage X (fp32 -> bf16), 128 rows x 128 k
    {
        int c4 = tid & 31;             // float4 column group
        int r0 = tid >> 5;             // 0..7
        #pragma unroll
        for (int p = 0; p < 16; p++) {
            int r = r0 + p * 8;
            int grow = row0 + r;
            float4 v = make_float4(0.f, 0.f, 0.f, 0.f);
            if (grow < Nrows) v = *(const float4*)&X[(size_t)grow * 128 + c4 * 4];
            short4 b;
            b.x = f2bf(v.x); b.y = f2bf(v.y); b.z = f2bf(v.z); b.w = f2bf(v.w);
            *(short4*)&Xs[r * KP + c4 * 4] = b;
        }
    }
    // stage Wt (already bf16): DOUT rows x 128 k, 8 shorts per load unit
    {
        constexpr int UNITS = DOUT * 16;       // 16 units (8 shorts) per row
        #pragma unroll
        for (int p = 0; p < UNITS / 256; p++) {
            int u = tid + p * 256;
            int n = u >> 4;
            int kc = (u & 15) * 8;
            bf16x8 v = *(const bf16x8*)&Wt[n * 128 + kc];
            *(bf16x8*)&Ws[n * KP + kc] = v;
        }
    }
    __syncthreads();

    const int lane = tid & 63;
    const int wv = tid >> 6;
    const int m0 = wv * 32;
    const int ln = lane & 15;
    const int quad = lane >> 4;

    floatx4 acc[2][CT];
    #pragma unroll
    for (int mt = 0; mt < 2; mt++)
        #pragma unroll
        for (int ct = 0; ct < CT; ct++) acc[mt][ct] = (floatx4){0.f, 0.f, 0.f, 0.f};

    #pragma unroll
    for (int ks = 0; ks < 4; ks++) {
        int ko = ks * 32 + quad * 8;
        bf16x8 a0 = *(const bf16x8*)&Xs[(m0 + ln) * KP + ko];
        bf16x8 a1 = *(const bf16x8*)&Xs[(m0 + 16 + ln) * KP + ko];
        #pragma unroll
        for (int ct = 0; ct < CT; ct++) {
            bf16x8 b = *(const bf16x8*)&Ws[(ct * 16 + ln) * KP + ko];
            acc[0][ct] = __builtin_amdgcn_mfma_f32_16x16x32_bf16(a0, b, acc[0][ct], 0, 0, 0);
            acc[1][ct] = __builtin_amdgcn_mfma_f32_16x16x32_bf16(a1, b, acc[1][ct], 0, 0, 0);
        }
    }

    // C/D layout: col = lane&15, row = quad*4 + reg
    #pragma unroll
    for (int mt = 0; mt < 2; mt++) {
        #pragma unroll
        for (int r = 0; r < 4; r++) {
            int grow = row0 + m0 + mt * 16 + quad * 4 + r;
            if (grow < Nrows) {
                #pragma unroll
                for (int ct = 0; ct < CT; ct++)
                    Hout[(size_t)grow * DOUT + ct * 16 + ln] = f2bf(acc[mt][ct][r]);
            }
        }
    }
}

// ---------------- attention logits (8 heads x 16), bf16 H ----------------

__global__ void k_al(const short* __restrict__ Hb, const float* __restrict__ a_s,
                     const float* __restrict__ a_d, float* __restrict__ als,
                     float* __restrict__ ald, int N) {
    int i = blockIdx.x * blockDim.x + threadIdx.x;
    if (i >= N * 8) return;
    int n = i >> 3, h = i & 7;
    const int4* hp = (const int4*)(Hb + (size_t)n * 128 + h * 16);
    int4 q0 = hp[0], q1 = hp[1];
    float hv[16] = {bflo(q0.x), bfhi(q0.x), bflo(q0.y), bfhi(q0.y),
                    bflo(q0.z), bfhi(q0.z), bflo(q0.w), bfhi(q0.w),
                    bflo(q1.x), bfhi(q1.x), bflo(q1.y), bfhi(q1.y),
                    bflo(q1.z), bfhi(q1.z), bflo(q1.w), bfhi(q1.w)};
    const float* sp = a_s + h * 16;
    const float* dp = a_d + h * 16;
    float ss = 0.f, sd = 0.f;
    #pragma unroll
    for (int j = 0; j < 16; j++) {
        ss += hv[j] * sp[j];
        sd += hv[j] * dp[j];
    }
    als[i] = ss;
    ald[i] = sd;
}

// ---------------- per-edge softmax weights (unnormalized) ----------------

__global__ void k_edgew8(const int* __restrict__ col, const int* __restrict__ dstarr,
                         const float* __restrict__ als, const float* __restrict__ ald,
                         float* __restrict__ w, int Etot) {
    int i = blockIdx.x * blockDim.x + threadIdx.x;
    if (i >= Etot * 8) return;
    int j = i >> 3, h = i & 7;
    int s = col[j], d = dstarr[j];
    float e = als[s * 8 + h] + ald[d * 8 + h];
    e = LRELU(e);
    w[i] = __expf(e);
}

__global__ void k_edgew1(const int* __restrict__ col, const int* __restrict__ dstarr,
                         const float* __restrict__ als, const float* __restrict__ ald,
                         float* __restrict__ w, int Etot) {
    int j = blockIdx.x * blockDim.x + threadIdx.x;
    if (j >= Etot) return;
    float e = als[col[j]] + ald[dstarr[j]];
    e = LRELU(e);
    w[j] = __expf(e);
}

// ---------------- single-pass aggregate, bf16 H rows, 64 lanes/node ----------------

__global__ __launch_bounds__(256) void k_agg(const int* __restrict__ rowptr,
                                             const int* __restrict__ col,
                                             const short* __restrict__ Hb,
                                             const float* __restrict__ w,
                                             const float* __restrict__ bias,
                                             float* __restrict__ out, int N) {
    int node = blockIdx.x * 4 + (threadIdx.x >> 6);
    int lane = threadIdx.x & 63;
    if (node >= N) return;
    int h = lane >> 3;                    // head of dims {2*lane, 2*lane+1}
    int beg = rowptr[node], end = rowptr[node + 1];
    const int* Hi = (const int*)Hb;       // bf16x2 per int, row stride 64 ints
    float ssum = 0.f, a0 = 0.f, a1 = 0.f;
    int j = beg;
    for (; j + 4 <= end; j += 4) {
        int c0 = col[j], c1 = col[j + 1], c2 = col[j + 2], c3 = col[j + 3];
        float w0 = w[j * 8 + h];
        float w1 = w[(j + 1) * 8 + h];
        float w2 = w[(j + 2) * 8 + h];
        float w3 = w[(j + 3) * 8 + h];
        int p0 = Hi[(c0 << 6) + lane];
        int p1 = Hi[(c1 << 6) + lane];
        int p2 = Hi[(c2 << 6) + lane];
        int p3 = Hi[(c3 << 6) + lane];
        ssum += (w0 + w1) + (w2 + w3);
        a0 += w0 * bflo(p0); a1 += w0 * bfhi(p0);
        a0 += w1 * bflo(p1); a1 += w1 * bfhi(p1);
        a0 += w2 * bflo(p2); a1 += w2 * bfhi(p2);
        a0 += w3 * bflo(p3); a1 += w3 * bfhi(p3);
    }
    for (; j < end; j++) {
        int c = col[j];
        float wv = w[j * 8 + h];
        int p = Hi[(c << 6) + lane];
        ssum += wv;
        a0 += wv * bflo(p); a1 += wv * bfhi(p);
    }
    float inv = 1.f / (ssum + 1e-16f);
    float2 o;
    o.x = a0 * inv + bias[2 * lane];
    o.y = a1 * inv + bias[2 * lane + 1];
    ((float2*)out)[(size_t)node * 64 + lane] = o;
}

// ---------------- BatchNorm stats ----------------

__global__ void k_bnstats(const float* __restrict__ V, int N, float* __restrict__ sums) {
    int col = threadIdx.x & 127;
    int row0 = blockIdx.x * 2 + (threadIdx.x >> 7);
    int stride = gridDim.x * 2;
    float s = 0.f, q = 0.f;
    for (int n = row0; n < N; n += stride) {
        float v = V[(size_t)n * 128 + col];
        s += v;
        q += v * v;
    }
    atomicAdd(&sums[col], s);
    atomicAdd(&sums[128 + col], q);
}

// ---------------- BN apply + ReLU + residual ----------------

__global__ void k_bnapply(const float* __restrict__ V, const float* __restrict__ sums,
                          const float* __restrict__ g, const float* __restrict__ bt,
                          const float* __restrict__ xres, float* __restrict__ xout,
                          int N, float invN) {
    int i = blockIdx.x * blockDim.x + threadIdx.x;
    if (i >= N * 32) return;
    int c0 = (i & 31) * 4;
    float4 v = ((const float4*)V)[i];
    float4 xr = ((const float4*)xres)[i];
    float vv[4] = {v.x, v.y, v.z, v.w};
    float xx[4] = {xr.x, xr.y, xr.z, xr.w};
    float oo[4];
    #pragma unroll
    for (int j = 0; j < 4; j++) {
        int c = c0 + j;
        float mu = sums[c] * invN;
        float var = sums[128 + c] * invN - mu * mu;
        float y = (vv[j] - mu) * rsqrtf(var + 1e-5f) * g[c] + bt[c];
        oo[j] = fmaxf(y, 0.f) + xx[j];
    }
    ((float4*)xout)[i] = make_float4(oo[0], oo[1], oo[2], oo[3]);
}

// ---------------- layer-2 logits (1 head, 64 dims), bf16 H2 ----------------

__global__ void k_al2(const short* __restrict__ Hb2, const float* __restrict__ as2,
                      const float* __restrict__ ad2, float* __restrict__ als,
                      float* __restrict__ ald, int N) {
    int node = blockIdx.x * 4 + (threadIdx.x >> 6);
    int lc = threadIdx.x & 63;
    if (node >= N) return;
    float v = bf2f(((const unsigned short*)Hb2)[(size_t)node * 64 + lc]);
    float s = v * as2[lc];
    float d = v * ad2[lc];
    #pragma unroll
    for (int off = 32; off; off >>= 1) {
        s += __shfl_xor(s, off, 64);
        d += __shfl_xor(d, off, 64);
    }
    if (lc == 0) { als[node] = s; ald[node] = d; }
}

// ---------------- layer-2 single-pass aggregate + LayerNorm, bf16 H2 ----------------

__global__ void k_agg2ln(const int* __restrict__ rowptr, const int* __restrict__ col,
                         const short* __restrict__ Hb2, const float* __restrict__ w,
                         const float* __restrict__ b2,
                         const float* __restrict__ lng, const float* __restrict__ lnb,
                         float* __restrict__ out, int N) {
    int node = blockIdx.x * 4 + (threadIdx.x >> 6);
    int lc = threadIdx.x & 63;
    if (node >= N) return;
    const unsigned short* H = (const unsigned short*)Hb2;
    int beg = rowptr[node], end = rowptr[node + 1];
    float ssum = 0.f, acc = 0.f;
    int j = beg;
    for (; j + 4 <= end; j += 4) {
        int c0 = col[j], c1 = col[j + 1], c2 = col[j + 2], c3 = col[j + 3];
        float w0 = w[j], w1 = w[j + 1], w2 = w[j + 2], w3 = w[j + 3];
        float h0 = bf2f(H[(c0 << 6) + lc]);
        float h1 = bf2f(H[(c1 << 6) + lc]);
        float h2 = bf2f(H[(c2 << 6) + lc]);
        float h3 = bf2f(H[(c3 << 6) + lc]);
        ssum += (w0 + w1) + (w2 + w3);
        acc += w0 * h0;
        acc += w1 * h1;
        acc += w2 * h2;
        acc += w3 * h3;
    }
    for (; j < end; j++) {
        int c = col[j];
        float wv = w[j];
        ssum += wv;
        acc += wv * bf2f(H[(c << 6) + lc]);
    }
    float v = acc / (ssum + 1e-16f) + b2[lc];
    float su = v, sq = v * v;
    #pragma unroll
    for (int off = 32; off; off >>= 1) {
        su += __shfl_xor(su, off, 64);
        sq += __shfl_xor(sq, off, 64);
    }
    float mu = su * (1.f / 64.f);
    float var = sq * (1.f / 64.f) - mu * mu;
    float r = rsqrtf(var + 1e-5f);
    out[(size_t)node * 64 + lc] = (v - mu) * r * lng[lc] + lnb[lc];
}

// ---------------- launch ----------------

extern "C" void kernel_launch(void* const* d_in, const int* in_sizes, int n_in,
                              void* d_out, int out_size, void* d_ws, size_t ws_size,
                              hipStream_t stream) {
    const float* x   = (const float*)d_in[0];
    const int*   ei  = (const int*)d_in[1];
    const float* W0  = (const float*)d_in[2];
    const float* as0 = (const float*)d_in[3];
    const float* ad0 = (const float*)d_in[4];
    const float* b0  = (const float*)d_in[5];
    const float* g0  = (const float*)d_in[6];
    const float* bt0 = (const float*)d_in[7];
    const float* W1  = (const float*)d_in[8];
    const float* as1 = (const float*)d_in[9];
    const float* ad1 = (const float*)d_in[10];
    const float* b1  = (const float*)d_in[11];
    const float* g1  = (const float*)d_in[12];
    const float* bt1 = (const float*)d_in[13];
    const float* W2  = (const float*)d_in[14];
    const float* as2 = (const float*)d_in[15];
    const float* ad2 = (const float*)d_in[16];
    const float* b2  = (const float*)d_in[17];
    const float* lng = (const float*)d_in[18];
    const float* lnb = (const float*)d_in[19];

    const int N = in_sizes[0] / 128;
    const int E = in_sizes[1] / 2;
    const int Etot = E + N;

    char* p = (char*)d_ws;
    auto carve = [&](size_t bytes) {
        void* q = (void*)p;
        p += (bytes + 255) & ~(size_t)255;
        return q;
    };
    short* Hb     = (short*)carve((size_t)N * 128 * 2);
    float* agg    = (float*)carve((size_t)N * 128 * 4);
    float* x1     = (float*)carve((size_t)N * 128 * 4);
    float* als    = (float*)carve((size_t)N * 8 * 4);
    float* ald    = (float*)carve((size_t)N * 8 * 4);
    int*   rowptr = (int*)carve((size_t)(N + 1) * 4);
    int*   cursor = (int*)carve((size_t)(N + 1) * 4);
    int*   deg    = (int*)carve((size_t)N * 4);
    int*   col    = (int*)carve((size_t)Etot * 4);
    int*   dstarr = (int*)carve((size_t)Etot * 4);
    float* w      = (float*)carve((size_t)Etot * 8 * 4);
    float* bns    = (float*)carve(256 * 4);
    short* Wt0    = (short*)carve(128 * 128 * 2);
    short* Wt1    = (short*)carve(128 * 128 * 2);
    short* Wt2    = (short*)carve(64 * 128 * 2);

    const float invN = 1.f / (float)N;
    const int eb = (E + N + 255) / 256;

    // weight prep (independent)
    k_wprep<<<(128 * 128 + 255) / 256, 256, 0, stream>>>(W0, Wt0, 128);
    k_wprep<<<(128 * 128 + 255) / 256, 256, 0, stream>>>(W1, Wt1, 128);
    k_wprep<<<(64 * 128 + 255) / 256, 256, 0, stream>>>(W2, Wt2, 64);

    // CSR build
    hipMemsetAsync(deg, 0, (size_t)N * 4, stream);
    k_count<<<eb, 256, 0, stream>>>(ei + E, E, N, deg);
    k_scan<<<1, 1024, 0, stream>>>(deg, N, Etot, rowptr, cursor);
    k_fill<<<eb, 256, 0, stream>>>(ei, ei + E, E, N, cursor, col, dstarr);

    const int gb = (N + 127) / 128;
    const int ewb8 = (Etot * 8 + 255) / 256;
    const int ewb1 = (Etot + 255) / 256;

    // ---- layer 0 ----
    k_gemm<128><<<gb, 256, 0, stream>>>(x, Wt0, Hb, N);
    k_al<<<(N * 8 + 255) / 256, 256, 0, stream>>>(Hb, as0, ad0, als, ald, N);
    k_edgew8<<<ewb8, 256, 0, stream>>>(col, dstarr, als, ald, w, Etot);
    k_agg<<<(N + 3) / 4, 256, 0, stream>>>(rowptr, col, Hb, w, b0, agg, N);
    hipMemsetAsync(bns, 0, 256 * 4, stream);
    k_bnstats<<<256, 256, 0, stream>>>(agg, N, bns);
    k_bnapply<<<(N * 32 + 255) / 256, 256, 0, stream>>>(agg, bns, g0, bt0, x, x1, N, invN);

    // ---- layer 1 ----
    k_gemm<128><<<gb, 256, 0, stream>>>(x1, Wt1, Hb, N);
    k_al<<<(N * 8 + 255) / 256, 256, 0, stream>>>(Hb, as1, ad1, als, ald, N);
    k_edgew8<<<ewb8, 256, 0, stream>>>(col, dstarr, als, ald, w, Etot);
    k_agg<<<(N + 3) / 4, 256, 0, stream>>>(rowptr, col, Hb, w, b1, agg, N);
    hipMemsetAsync(bns, 0, 256 * 4, stream);
    k_bnstats<<<256, 256, 0, stream>>>(agg, N, bns);
    k_bnapply<<<(N * 32 + 255) / 256, 256, 0, stream>>>(agg, bns, g1, bt1, x1, x1, N, invN);

    // ---- layer 2 + LayerNorm ----
    k_gemm<64><<<gb, 256, 0, stream>>>(x1, Wt2, Hb, N);
    k_al2<<<(N + 3) / 4, 256, 0, stream>>>(Hb, as2, ad2, als, ald, N);
    k_edgew1<<<ewb1, 256, 0, stream>>>(col, dstarr, als, ald, w, Etot);
    k_agg2ln<<<(N + 3) / 4, 256, 0, stream>>>(rowptr, col, Hb, w, b2, lng, lnb,
                                              (float*)d_out, N);
}

// Round 4
// 673.529 us; speedup vs baseline: 2.1616x; 1.1334x over previous
//
#include <hip/hip_runtime.h>
#include <hip/hip_bf16.h>

#define LRELU(e) ((e) > 0.f ? (e) : 0.2f * (e))

typedef __attribute__((ext_vector_type(8))) short bf16x8;
typedef __attribute__((ext_vector_type(4))) float floatx4;

__device__ inline short f2bf(float f) {
    union { float f; unsigned u; } v; v.f = f;
    unsigned r = v.u + 0x7fffu + ((v.u >> 16) & 1u);
    return (short)(r >> 16);
}
__device__ inline float bflo(int p) {
    union { unsigned u; float f; } v; v.u = (unsigned)p << 16; return v.f;
}
__device__ inline float bfhi(int p) {
    union { unsigned u; float f; } v; v.u = (unsigned)p & 0xffff0000u; return v.f;
}
__device__ inline float bf2f(unsigned short s) {
    union { unsigned u; float f; } v; v.u = (unsigned)s << 16; return v.f;
}

// ---------------- CSR build ----------------

__global__ void k_count(const int* __restrict__ dstE, int E, int N, int* __restrict__ deg) {
    int i = blockIdx.x * blockDim.x + threadIdx.x;
    if (i < E) atomicAdd(&deg[dstE[i]], 1);
    else if (i < E + N) atomicAdd(&deg[i - E], 1);
}

// 3-phase device-wide exclusive scan of deg[N] -> rowptr/cursor
constexpr int SC = 2048;   // elements per scan block

__global__ __launch_bounds__(256) void k_scan1(const int* __restrict__ deg, int N,
                                               int* __restrict__ partial) {
    int base = blockIdx.x * SC;
    int t = threadIdx.x;
    int s = 0;
    #pragma unroll
    for (int p = 0; p < SC / 256; p++) {
        int i = base + t + p * 256;
        if (i < N) s += deg[i];
    }
    #pragma unroll
    for (int off = 32; off; off >>= 1) s += __shfl_xor(s, off, 64);
    __shared__ int ws[4];
    int lane = t & 63, wid = t >> 6;
    if (lane == 0) ws[wid] = s;
    __syncthreads();
    if (t == 0) partial[blockIdx.x] = ws[0] + ws[1] + ws[2] + ws[3];
}

__global__ __launch_bounds__(256) void k_scan2(int* __restrict__ partial, int nb) {
    int t = threadIdx.x;
    int v = (t < nb) ? partial[t] : 0;
    int lane = t & 63, wid = t >> 6;
    int x = v;
    #pragma unroll
    for (int off = 1; off < 64; off <<= 1) {
        int y = __shfl_up(x, off, 64);
        if (lane >= off) x += y;
    }
    __shared__ int wsum[4];
    if (lane == 63) wsum[wid] = x;
    __syncthreads();
    int add = 0;
    for (int i = 0; i < wid; i++) add += wsum[i];
    if (t < nb) partial[t] = x + add - v;   // exclusive
}

__global__ __launch_bounds__(256) void k_scan3(const int* __restrict__ deg, int N, int Etot,
                                               const int* __restrict__ partial,
                                               int* __restrict__ rowptr,
                                               int* __restrict__ cursor) {
    int base = blockIdx.x * SC;
    int t = threadIdx.x;
    int i0 = base + t * 8;
    int v[8];
    int s = 0;
    #pragma unroll
    for (int p = 0; p < 8; p++) {
        int i = i0 + p;
        v[p] = (i < N) ? deg[i] : 0;
        s += v[p];
    }
    int lane = t & 63, wid = t >> 6;
    int x = s;
    #pragma unroll
    for (int off = 1; off < 64; off <<= 1) {
        int y = __shfl_up(x, off, 64);
        if (lane >= off) x += y;
    }
    __shared__ int wsum[4];
    if (lane == 63) wsum[wid] = x;
    __syncthreads();
    int add = 0;
    for (int i = 0; i < wid; i++) add += wsum[i];
    int excl = x - s + add + partial[blockIdx.x];
    #pragma unroll
    for (int p = 0; p < 8; p++) {
        int i = i0 + p;
        if (i < N) { rowptr[i] = excl; cursor[i] = excl; }
        excl += v[p];
    }
    if (blockIdx.x == 0 && t == 0) rowptr[N] = Etot;
}

__global__ void k_fill(const int* __restrict__ srcE, const int* __restrict__ dstE,
                       int E, int N, int* __restrict__ cursor, int* __restrict__ col,
                       int* __restrict__ dstarr) {
    int i = blockIdx.x * blockDim.x + threadIdx.x;
    if (i < E) {
        int d = dstE[i];
        int p = atomicAdd(&cursor[d], 1);
        col[p] = srcE[i];
        dstarr[p] = d;
    } else if (i < E + N) {
        int d = i - E;
        int p = atomicAdd(&cursor[d], 1);
        col[p] = d;
        dstarr[p] = d;
    }
}

// ---------------- W prep: all three weights in one launch ----------------
// W [128,DOUT] fp32 -> Wt [DOUT,128] bf16 (transposed)

__global__ void k_wprep(const float* __restrict__ W0, const float* __restrict__ W1,
                        const float* __restrict__ W2, short* __restrict__ Wt0,
                        short* __restrict__ Wt1, short* __restrict__ Wt2) {
    int i = blockIdx.x * blockDim.x + threadIdx.x;
    if (i < 128 * 128) {
        int n = i >> 7, k = i & 127;
        Wt0[i] = f2bf(W0[k * 128 + n]);
        Wt1[i] = f2bf(W1[k * 128 + n]);
    } else {
        i -= 128 * 128;
        if (i < 64 * 128) {
            int n = i >> 7, k = i & 127;
            Wt2[i] = f2bf(W2[k * 64 + n]);
        }
    }
}

// ---------------- MFMA bf16 GEMM: [N,128] @ [128,DOUT] -> bf16 Hout ----------------

template <int DOUT>
__global__ __launch_bounds__(256) void k_gemm(const float* __restrict__ X,
                                              const short* __restrict__ Wt,
                                              short* __restrict__ Hout, int Nrows) {
    constexpr int KP = 136;
    constexpr int CT = DOUT / 16;
    __shared__ __align__(16) short Xs[128 * KP];
    __shared__ __align__(16) short Ws[DOUT * KP];

    const int tid = threadIdx.x;
    const int row0 = blockIdx.x * 128;

    {
        int c4 = tid & 31;
        int r0 = tid >> 5;
        #pragma unroll
        for (int p = 0; p < 16; p++) {
            int r = r0 + p * 8;
            int grow = row0 + r;
            float4 v = make_float4(0.f, 0.f, 0.f, 0.f);
            if (grow < Nrows) v = *(const float4*)&X[(size_t)grow * 128 + c4 * 4];
            short4 b;
            b.x = f2bf(v.x); b.y = f2bf(v.y); b.z = f2bf(v.z); b.w = f2bf(v.w);
            *(short4*)&Xs[r * KP + c4 * 4] = b;
        }
    }
    {
        constexpr int UNITS = DOUT * 16;
        #pragma unroll
        for (int p = 0; p < UNITS / 256; p++) {
            int u = tid + p * 256;
            int n = u >> 4;
            int kc = (u & 15) * 8;
            bf16x8 v = *(const bf16x8*)&Wt[n * 128 + kc];
            *(bf16x8*)&Ws[n * KP + kc] = v;
        }
    }
    __syncthreads();

    const int lane = tid & 63;
    const int wv = tid >> 6;
    const int m0 = wv * 32;
    const int ln = lane & 15;
    const int quad = lane >> 4;

    floatx4 acc[2][CT];
    #pragma unroll
    for (int mt = 0; mt < 2; mt++)
        #pragma unroll
        for (int ct = 0; ct < CT; ct++) acc[mt][ct] = (floatx4){0.f, 0.f, 0.f, 0.f};

    #pragma unroll
    for (int ks = 0; ks < 4; ks++) {
        int ko = ks * 32 + quad * 8;
        bf16x8 a0 = *(const bf16x8*)&Xs[(m0 + ln) * KP + ko];
        bf16x8 a1 = *(const bf16x8*)&Xs[(m0 + 16 + ln) * KP + ko];
        #pragma unroll
        for (int ct = 0; ct < CT; ct++) {
            bf16x8 b = *(const bf16x8*)&Ws[(ct * 16 + ln) * KP + ko];
            acc[0][ct] = __builtin_amdgcn_mfma_f32_16x16x32_bf16(a0, b, acc[0][ct], 0, 0, 0);
            acc[1][ct] = __builtin_amdgcn_mfma_f32_16x16x32_bf16(a1, b, acc[1][ct], 0, 0, 0);
        }
    }

    #pragma unroll
    for (int mt = 0; mt < 2; mt++) {
        #pragma unroll
        for (int r = 0; r < 4; r++) {
            int grow = row0 + m0 + mt * 16 + quad * 4 + r;
            if (grow < Nrows) {
                #pragma unroll
                for (int ct = 0; ct < CT; ct++)
                    Hout[(size_t)grow * DOUT + ct * 16 + ln] = f2bf(acc[mt][ct][r]);
            }
        }
    }
}

// ---------------- attention logits (8 heads x 16), bf16 H ----------------

__global__ void k_al(const short* __restrict__ Hb, const float* __restrict__ a_s,
                     const float* __restrict__ a_d, float* __restrict__ als,
                     float* __restrict__ ald, int N) {
    int i = blockIdx.x * blockDim.x + threadIdx.x;
    if (i >= N * 8) return;
    int n = i >> 3, h = i & 7;
    const int4* hp = (const int4*)(Hb + (size_t)n * 128 + h * 16);
    int4 q0 = hp[0], q1 = hp[1];
    float hv[16] = {bflo(q0.x), bfhi(q0.x), bflo(q0.y), bfhi(q0.y),
                    bflo(q0.z), bfhi(q0.z), bflo(q0.w), bfhi(q0.w),
                    bflo(q1.x), bfhi(q1.x), bflo(q1.y), bfhi(q1.y),
                    bflo(q1.z), bfhi(q1.z), bflo(q1.w), bfhi(q1.w)};
    const float* sp = a_s + h * 16;
    const float* dp = a_d + h * 16;
    float ss = 0.f, sd = 0.f;
    #pragma unroll
    for (int j = 0; j < 16; j++) {
        ss += hv[j] * sp[j];
        sd += hv[j] * dp[j];
    }
    als[i] = ss;
    ald[i] = sd;
}

// ---------------- per-edge softmax weights (unnormalized) ----------------

__global__ void k_edgew8(const int* __restrict__ col, const int* __restrict__ dstarr,
                         const float* __restrict__ als, const float* __restrict__ ald,
                         float* __restrict__ w, int Etot) {
    int i = blockIdx.x * blockDim.x + threadIdx.x;
    if (i >= Etot * 8) return;
    int j = i >> 3, h = i & 7;
    int s = col[j], d = dstarr[j];
    float e = als[s * 8 + h] + ald[d * 8 + h];
    e = LRELU(e);
    w[i] = __expf(e);
}

__global__ void k_edgew1(const int* __restrict__ col, const int* __restrict__ dstarr,
                         const float* __restrict__ als, const float* __restrict__ ald,
                         float* __restrict__ w, int Etot) {
    int j = blockIdx.x * blockDim.x + threadIdx.x;
    if (j >= Etot) return;
    float e = als[col[j]] + ald[dstarr[j]];
    e = LRELU(e);
    w[j] = __expf(e);
}

// ---------------- single-pass aggregate, bf16 H rows, 64 lanes/node ----------------

__global__ __launch_bounds__(256) void k_agg(const int* __restrict__ rowptr,
                                             const int* __restrict__ col,
                                             const short* __restrict__ Hb,
                                             const float* __restrict__ w,
                                             const float* __restrict__ bias,
                                             float* __restrict__ out, int N) {
    int node = blockIdx.x * 4 + (threadIdx.x >> 6);
    int lane = threadIdx.x & 63;
    if (node >= N) return;
    int h = lane >> 3;
    int beg = rowptr[node], end = rowptr[node + 1];
    const int* Hi = (const int*)Hb;
    float ssum = 0.f, a0 = 0.f, a1 = 0.f;
    int j = beg;
    for (; j + 4 <= end; j += 4) {
        int c0 = col[j], c1 = col[j + 1], c2 = col[j + 2], c3 = col[j + 3];
        float w0 = w[j * 8 + h];
        float w1 = w[(j + 1) * 8 + h];
        float w2 = w[(j + 2) * 8 + h];
        float w3 = w[(j + 3) * 8 + h];
        int p0 = Hi[(c0 << 6) + lane];
        int p1 = Hi[(c1 << 6) + lane];
        int p2 = Hi[(c2 << 6) + lane];
        int p3 = Hi[(c3 << 6) + lane];
        ssum += (w0 + w1) + (w2 + w3);
        a0 += w0 * bflo(p0); a1 += w0 * bfhi(p0);
        a0 += w1 * bflo(p1); a1 += w1 * bfhi(p1);
        a0 += w2 * bflo(p2); a1 += w2 * bfhi(p2);
        a0 += w3 * bflo(p3); a1 += w3 * bfhi(p3);
    }
    for (; j < end; j++) {
        int c = col[j];
        float wv = w[j * 8 + h];
        int p = Hi[(c << 6) + lane];
        ssum += wv;
        a0 += wv * bflo(p); a1 += wv * bfhi(p);
    }
    float inv = 1.f / (ssum + 1e-16f);
    float2 o;
    o.x = a0 * inv + bias[2 * lane];
    o.y = a1 * inv + bias[2 * lane + 1];
    ((float2*)out)[(size_t)node * 64 + lane] = o;
}

// ---------------- BatchNorm stats ----------------

__global__ void k_bnstats(const float* __restrict__ V, int N, float* __restrict__ sums) {
    int col = threadIdx.x & 127;
    int row0 = blockIdx.x * 2 + (threadIdx.x >> 7);
    int stride = gridDim.x * 2;
    float s = 0.f, q = 0.f;
    for (int n = row0; n < N; n += stride) {
        float v = V[(size_t)n * 128 + col];
        s += v;
        q += v * v;
    }
    atomicAdd(&sums[col], s);
    atomicAdd(&sums[128 + col], q);
}

// ---------------- BN apply + ReLU + residual ----------------

__global__ void k_bnapply(const float* __restrict__ V, const float* __restrict__ sums,
                          const float* __restrict__ g, const float* __restrict__ bt,
                          const float* __restrict__ xres, float* __restrict__ xout,
                          int N, float invN) {
    int i = blockIdx.x * blockDim.x + threadIdx.x;
    if (i >= N * 32) return;
    int c0 = (i & 31) * 4;
    float4 v = ((const float4*)V)[i];
    float4 xr = ((const float4*)xres)[i];
    float vv[4] = {v.x, v.y, v.z, v.w};
    float xx[4] = {xr.x, xr.y, xr.z, xr.w};
    float oo[4];
    #pragma unroll
    for (int j = 0; j < 4; j++) {
        int c = c0 + j;
        float mu = sums[c] * invN;
        float var = sums[128 + c] * invN - mu * mu;
        float y = (vv[j] - mu) * rsqrtf(var + 1e-5f) * g[c] + bt[c];
        oo[j] = fmaxf(y, 0.f) + xx[j];
    }
    ((float4*)xout)[i] = make_float4(oo[0], oo[1], oo[2], oo[3]);
}

// ---------------- layer-2 logits (1 head, 64 dims), bf16 H2 ----------------

__global__ void k_al2(const short* __restrict__ Hb2, const float* __restrict__ as2,
                      const float* __restrict__ ad2, float* __restrict__ als,
                      float* __restrict__ ald, int N) {
    int node = blockIdx.x * 4 + (threadIdx.x >> 6);
    int lc = threadIdx.x & 63;
    if (node >= N) return;
    float v = bf2f(((const unsigned short*)Hb2)[(size_t)node * 64 + lc]);
    float s = v * as2[lc];
    float d = v * ad2[lc];
    #pragma unroll
    for (int off = 32; off; off >>= 1) {
        s += __shfl_xor(s, off, 64);
        d += __shfl_xor(d, off, 64);
    }
    if (lc == 0) { als[node] = s; ald[node] = d; }
}

// ---------------- layer-2 single-pass aggregate + LayerNorm, bf16 H2 ----------------

__global__ void k_agg2ln(const int* __restrict__ rowptr, const int* __restrict__ col,
                         const short* __restrict__ Hb2, const float* __restrict__ w,
                         const float* __restrict__ b2,
                         const float* __restrict__ lng, const float* __restrict__ lnb,
                         float* __restrict__ out, int N) {
    int node = blockIdx.x * 4 + (threadIdx.x >> 6);
    int lc = threadIdx.x & 63;
    if (node >= N) return;
    const unsigned short* H = (const unsigned short*)Hb2;
    int beg = rowptr[node], end = rowptr[node + 1];
    float ssum = 0.f, acc = 0.f;
    int j = beg;
    for (; j + 4 <= end; j += 4) {
        int c0 = col[j], c1 = col[j + 1], c2 = col[j + 2], c3 = col[j + 3];
        float w0 = w[j], w1 = w[j + 1], w2 = w[j + 2], w3 = w[j + 3];
        float h0 = bf2f(H[(c0 << 6) + lc]);
        float h1 = bf2f(H[(c1 << 6) + lc]);
        float h2 = bf2f(H[(c2 << 6) + lc]);
        float h3 = bf2f(H[(c3 << 6) + lc]);
        ssum += (w0 + w1) + (w2 + w3);
        acc += w0 * h0;
        acc += w1 * h1;
        acc += w2 * h2;
        acc += w3 * h3;
    }
    for (; j < end; j++) {
        int c = col[j];
        float wv = w[j];
        ssum += wv;
        acc += wv * bf2f(H[(c << 6) + lc]);
    }
    float v = acc / (ssum + 1e-16f) + b2[lc];
    float su = v, sq = v * v;
    #pragma unroll
    for (int off = 32; off; off >>= 1) {
        su += __shfl_xor(su, off, 64);
        sq += __shfl_xor(sq, off, 64);
    }
    float mu = su * (1.f / 64.f);
    float var = sq * (1.f / 64.f) - mu * mu;
    float r = rsqrtf(var + 1e-5f);
    out[(size_t)node * 64 + lc] = (v - mu) * r * lng[lc] + lnb[lc];
}

// ---------------- launch ----------------

extern "C" void kernel_launch(void* const* d_in, const int* in_sizes, int n_in,
                              void* d_out, int out_size, void* d_ws, size_t ws_size,
                              hipStream_t stream) {
    const float* x   = (const float*)d_in[0];
    const int*   ei  = (const int*)d_in[1];
    const float* W0  = (const float*)d_in[2];
    const float* as0 = (const float*)d_in[3];
    const float* ad0 = (const float*)d_in[4];
    const float* b0  = (const float*)d_in[5];
    const float* g0  = (const float*)d_in[6];
    const float* bt0 = (const float*)d_in[7];
    const float* W1  = (const float*)d_in[8];
    const float* as1 = (const float*)d_in[9];
    const float* ad1 = (const float*)d_in[10];
    const float* b1  = (const float*)d_in[11];
    const float* g1  = (const float*)d_in[12];
    const float* bt1 = (const float*)d_in[13];
    const float* W2  = (const float*)d_in[14];
    const float* as2 = (const float*)d_in[15];
    const float* ad2 = (const float*)d_in[16];
    const float* b2  = (const float*)d_in[17];
    const float* lng = (const float*)d_in[18];
    const float* lnb = (const float*)d_in[19];

    const int N = in_sizes[0] / 128;
    const int E = in_sizes[1] / 2;
    const int Etot = E + N;

    char* p = (char*)d_ws;
    auto carve = [&](size_t bytes) {
        void* q = (void*)p;
        p += (bytes + 255) & ~(size_t)255;
        return q;
    };
    short* Hb     = (short*)carve((size_t)N * 128 * 2);
    float* agg    = (float*)carve((size_t)N * 128 * 4);
    float* x1     = (float*)carve((size_t)N * 128 * 4);
    float* als    = (float*)carve((size_t)N * 8 * 4);
    float* ald    = (float*)carve((size_t)N * 8 * 4);
    int*   rowptr = (int*)carve((size_t)(N + 1) * 4);
    int*   cursor = (int*)carve((size_t)(N + 1) * 4);
    int*   deg    = (int*)carve((size_t)N * 4);
    int*   col    = (int*)carve((size_t)Etot * 4);
    int*   dstarr = (int*)carve((size_t)Etot * 4);
    float* w      = (float*)carve((size_t)Etot * 8 * 4);
    float* bns    = (float*)carve(256 * 4);
    short* Wt0    = (short*)carve(128 * 128 * 2);
    short* Wt1    = (short*)carve(128 * 128 * 2);
    short* Wt2    = (short*)carve(64 * 128 * 2);
    int*   partial= (int*)carve(256 * 4);

    const float invN = 1.f / (float)N;
    const int eb = (E + N + 255) / 256;
    const int nsb = (N + SC - 1) / SC;

    // weight prep (one launch for all three)
    k_wprep<<<(128 * 128 + 64 * 128 + 255) / 256, 256, 0, stream>>>(W0, W1, W2, Wt0, Wt1, Wt2);

    // CSR build
    hipMemsetAsync(deg, 0, (size_t)N * 4, stream);
    k_count<<<eb, 256, 0, stream>>>(ei + E, E, N, deg);
    k_scan1<<<nsb, 256, 0, stream>>>(deg, N, partial);
    k_scan2<<<1, 256, 0, stream>>>(partial, nsb);
    k_scan3<<<nsb, 256, 0, stream>>>(deg, N, Etot, partial, rowptr, cursor);
    k_fill<<<eb, 256, 0, stream>>>(ei, ei + E, E, N, cursor, col, dstarr);

    const int gb = (N + 127) / 128;
    const int ewb8 = (Etot * 8 + 255) / 256;
    const int ewb1 = (Etot + 255) / 256;

    // ---- layer 0 ----
    k_gemm<128><<<gb, 256, 0, stream>>>(x, Wt0, Hb, N);
    k_al<<<(N * 8 + 255) / 256, 256, 0, stream>>>(Hb, as0, ad0, als, ald, N);
    k_edgew8<<<ewb8, 256, 0, stream>>>(col, dstarr, als, ald, w, Etot);
    k_agg<<<(N + 3) / 4, 256, 0, stream>>>(rowptr, col, Hb, w, b0, agg, N);
    hipMemsetAsync(bns, 0, 256 * 4, stream);
    k_bnstats<<<256, 256, 0, stream>>>(agg, N, bns);
    k_bnapply<<<(N * 32 + 255) / 256, 256, 0, stream>>>(agg, bns, g0, bt0, x, x1, N, invN);

    // ---- layer 1 ----
    k_gemm<128><<<gb, 256, 0, stream>>>(x1, Wt1, Hb, N);
    k_al<<<(N * 8 + 255) / 256, 256, 0, stream>>>(Hb, as1, ad1, als, ald, N);
    k_edgew8<<<ewb8, 256, 0, stream>>>(col, dstarr, als, ald, w, Etot);
    k_agg<<<(N + 3) / 4, 256, 0, stream>>>(rowptr, col, Hb, w, b1, agg, N);
    hipMemsetAsync(bns, 0, 256 * 4, stream);
    k_bnstats<<<256, 256, 0, stream>>>(agg, N, bns);
    k_bnapply<<<(N * 32 + 255) / 256, 256, 0, stream>>>(agg, bns, g1, bt1, x1, x1, N, invN);

    // ---- layer 2 + LayerNorm ----
    k_gemm<64><<<gb, 256, 0, stream>>>(x1, Wt2, Hb, N);
    k_al2<<<(N + 3) / 4, 256, 0, stream>>>(Hb, as2, ad2, als, ald, N);
    k_edgew1<<<ewb1, 256, 0, stream>>>(col, dstarr, als, ald, w, Etot);
    k_agg2ln<<<(N + 3) / 4, 256, 0, stream>>>(rowptr, col, Hb, w, b2, lng, lnb,
                                              (float*)d_out, N);
}

// Round 5
// 581.245 us; speedup vs baseline: 2.5048x; 1.1588x over previous
//
#include <hip/hip_runtime.h>
#include <hip/hip_bf16.h>

#define LRELU(e) ((e) > 0.f ? (e) : 0.2f * (e))

typedef __attribute__((ext_vector_type(8))) short bf16x8;
typedef __attribute__((ext_vector_type(4))) float floatx4;

__device__ inline short f2bf(float f) {
    union { float f; unsigned u; } v; v.f = f;
    unsigned r = v.u + 0x7fffu + ((v.u >> 16) & 1u);
    return (short)(r >> 16);
}
__device__ inline float bflo(int p) {
    union { unsigned u; float f; } v; v.u = (unsigned)p << 16; return v.f;
}
__device__ inline float bfhi(int p) {
    union { unsigned u; float f; } v; v.u = (unsigned)p & 0xffff0000u; return v.f;
}
__device__ inline float bf2f(unsigned short s) {
    union { unsigned u; float f; } v; v.u = (unsigned)s << 16; return v.f;
}

// ---------------- CSR build ----------------

__global__ void k_count(const int* __restrict__ dstE, int E, int N, int* __restrict__ deg) {
    int i = blockIdx.x * blockDim.x + threadIdx.x;
    if (i < E) atomicAdd(&deg[dstE[i]], 1);
    else if (i < E + N) atomicAdd(&deg[i - E], 1);
}

constexpr int SC = 2048;   // elements per scan block

__global__ __launch_bounds__(256) void k_scan1(const int* __restrict__ deg, int N,
                                               int* __restrict__ partial) {
    int base = blockIdx.x * SC;
    int t = threadIdx.x;
    int s = 0;
    #pragma unroll
    for (int p = 0; p < SC / 256; p++) {
        int i = base + t + p * 256;
        if (i < N) s += deg[i];
    }
    #pragma unroll
    for (int off = 32; off; off >>= 1) s += __shfl_xor(s, off, 64);
    __shared__ int ws[4];
    int lane = t & 63, wid = t >> 6;
    if (lane == 0) ws[wid] = s;
    __syncthreads();
    if (t == 0) partial[blockIdx.x] = ws[0] + ws[1] + ws[2] + ws[3];
}

__global__ __launch_bounds__(256) void k_scan2(int* __restrict__ partial, int nb) {
    int t = threadIdx.x;
    int v = (t < nb) ? partial[t] : 0;
    int lane = t & 63, wid = t >> 6;
    int x = v;
    #pragma unroll
    for (int off = 1; off < 64; off <<= 1) {
        int y = __shfl_up(x, off, 64);
        if (lane >= off) x += y;
    }
    __shared__ int wsum[4];
    if (lane == 63) wsum[wid] = x;
    __syncthreads();
    int add = 0;
    for (int i = 0; i < wid; i++) add += wsum[i];
    if (t < nb) partial[t] = x + add - v;   // exclusive
}

__global__ __launch_bounds__(256) void k_scan3(const int* __restrict__ deg, int N, int Etot,
                                               const int* __restrict__ partial,
                                               int* __restrict__ rowptr,
                                               int* __restrict__ cursor) {
    int base = blockIdx.x * SC;
    int t = threadIdx.x;
    int i0 = base + t * 8;
    int v[8];
    int s = 0;
    #pragma unroll
    for (int p = 0; p < 8; p++) {
        int i = i0 + p;
        v[p] = (i < N) ? deg[i] : 0;
        s += v[p];
    }
    int lane = t & 63, wid = t >> 6;
    int x = s;
    #pragma unroll
    for (int off = 1; off < 64; off <<= 1) {
        int y = __shfl_up(x, off, 64);
        if (lane >= off) x += y;
    }
    __shared__ int wsum[4];
    if (lane == 63) wsum[wid] = x;
    __syncthreads();
    int add = 0;
    for (int i = 0; i < wid; i++) add += wsum[i];
    int excl = x - s + add + partial[blockIdx.x];
    #pragma unroll
    for (int p = 0; p < 8; p++) {
        int i = i0 + p;
        if (i < N) { rowptr[i] = excl; cursor[i] = excl; }
        excl += v[p];
    }
    if (blockIdx.x == 0 && t == 0) rowptr[N] = Etot;
}

__global__ void k_fill(const int* __restrict__ srcE, const int* __restrict__ dstE,
                       int E, int N, int* __restrict__ cursor, int* __restrict__ col,
                       int* __restrict__ dstarr) {
    int i = blockIdx.x * blockDim.x + threadIdx.x;
    if (i < E) {
        int d = dstE[i];
        int p = atomicAdd(&cursor[d], 1);
        col[p] = srcE[i];
        dstarr[p] = d;
    } else if (i < E + N) {
        int d = i - E;
        int p = atomicAdd(&cursor[d], 1);
        col[p] = d;
        dstarr[p] = d;
    }
}

// ---------------- W prep ----------------

__global__ void k_wprep(const float* __restrict__ W0, const float* __restrict__ W1,
                        const float* __restrict__ W2, short* __restrict__ Wt0,
                        short* __restrict__ Wt1, short* __restrict__ Wt2) {
    int i = blockIdx.x * blockDim.x + threadIdx.x;
    if (i < 128 * 128) {
        int n = i >> 7, k = i & 127;
        Wt0[i] = f2bf(W0[k * 128 + n]);
        Wt1[i] = f2bf(W1[k * 128 + n]);
    } else {
        i -= 128 * 128;
        if (i < 64 * 128) {
            int n = i >> 7, k = i & 127;
            Wt2[i] = f2bf(W2[k * 64 + n]);
        }
    }
}

// ---------------- MFMA bf16 GEMM ----------------

template <int DOUT>
__global__ __launch_bounds__(256) void k_gemm(const float* __restrict__ X,
                                              const short* __restrict__ Wt,
                                              short* __restrict__ Hout, int Nrows) {
    constexpr int KP = 136;
    constexpr int CT = DOUT / 16;
    __shared__ __align__(16) short Xs[128 * KP];
    __shared__ __align__(16) short Ws[DOUT * KP];

    const int tid = threadIdx.x;
    const int row0 = blockIdx.x * 128;

    {
        int c4 = tid & 31;
        int r0 = tid >> 5;
        #pragma unroll
        for (int p = 0; p < 16; p++) {
            int r = r0 + p * 8;
            int grow = row0 + r;
            float4 v = make_float4(0.f, 0.f, 0.f, 0.f);
            if (grow < Nrows) v = *(const float4*)&X[(size_t)grow * 128 + c4 * 4];
            short4 b;
            b.x = f2bf(v.x); b.y = f2bf(v.y); b.z = f2bf(v.z); b.w = f2bf(v.w);
            *(short4*)&Xs[r * KP + c4 * 4] = b;
        }
    }
    {
        constexpr int UNITS = DOUT * 16;
        #pragma unroll
        for (int p = 0; p < UNITS / 256; p++) {
            int u = tid + p * 256;
            int n = u >> 4;
            int kc = (u & 15) * 8;
            bf16x8 v = *(const bf16x8*)&Wt[n * 128 + kc];
            *(bf16x8*)&Ws[n * KP + kc] = v;
        }
    }
    __syncthreads();

    const int lane = tid & 63;
    const int wv = tid >> 6;
    const int m0 = wv * 32;
    const int ln = lane & 15;
    const int quad = lane >> 4;

    floatx4 acc[2][CT];
    #pragma unroll
    for (int mt = 0; mt < 2; mt++)
        #pragma unroll
        for (int ct = 0; ct < CT; ct++) acc[mt][ct] = (floatx4){0.f, 0.f, 0.f, 0.f};

    #pragma unroll
    for (int ks = 0; ks < 4; ks++) {
        int ko = ks * 32 + quad * 8;
        bf16x8 a0 = *(const bf16x8*)&Xs[(m0 + ln) * KP + ko];
        bf16x8 a1 = *(const bf16x8*)&Xs[(m0 + 16 + ln) * KP + ko];
        #pragma unroll
        for (int ct = 0; ct < CT; ct++) {
            bf16x8 b = *(const bf16x8*)&Ws[(ct * 16 + ln) * KP + ko];
            acc[0][ct] = __builtin_amdgcn_mfma_f32_16x16x32_bf16(a0, b, acc[0][ct], 0, 0, 0);
            acc[1][ct] = __builtin_amdgcn_mfma_f32_16x16x32_bf16(a1, b, acc[1][ct], 0, 0, 0);
        }
    }

    #pragma unroll
    for (int mt = 0; mt < 2; mt++) {
        #pragma unroll
        for (int r = 0; r < 4; r++) {
            int grow = row0 + m0 + mt * 16 + quad * 4 + r;
            if (grow < Nrows) {
                #pragma unroll
                for (int ct = 0; ct < CT; ct++)
                    Hout[(size_t)grow * DOUT + ct * 16 + ln] = f2bf(acc[mt][ct][r]);
            }
        }
    }
}

// ---------------- attention logits (8 heads x 16), bf16 H ----------------

__global__ void k_al(const short* __restrict__ Hb, const float* __restrict__ a_s,
                     const float* __restrict__ a_d, float* __restrict__ als,
                     float* __restrict__ ald, int N) {
    int i = blockIdx.x * blockDim.x + threadIdx.x;
    if (i >= N * 8) return;
    int n = i >> 3, h = i & 7;
    const int4* hp = (const int4*)(Hb + (size_t)n * 128 + h * 16);
    int4 q0 = hp[0], q1 = hp[1];
    float hv[16] = {bflo(q0.x), bfhi(q0.x), bflo(q0.y), bfhi(q0.y),
                    bflo(q0.z), bfhi(q0.z), bflo(q0.w), bfhi(q0.w),
                    bflo(q1.x), bfhi(q1.x), bflo(q1.y), bfhi(q1.y),
                    bflo(q1.z), bfhi(q1.z), bflo(q1.w), bfhi(q1.w)};
    const float* sp = a_s + h * 16;
    const float* dp = a_d + h * 16;
    float ss = 0.f, sd = 0.f;
    #pragma unroll
    for (int j = 0; j < 16; j++) {
        ss += hv[j] * sp[j];
        sd += hv[j] * dp[j];
    }
    als[i] = ss;
    ald[i] = sd;
}

// ---------------- per-edge softmax weights (unnormalized) ----------------

__global__ void k_edgew8(const int* __restrict__ col, const int* __restrict__ dstarr,
                         const float* __restrict__ als, const float* __restrict__ ald,
                         float* __restrict__ w, int Etot) {
    int i = blockIdx.x * blockDim.x + threadIdx.x;
    if (i >= Etot * 8) return;
    int j = i >> 3, h = i & 7;
    int s = col[j], d = dstarr[j];
    float e = als[s * 8 + h] + ald[d * 8 + h];
    e = LRELU(e);
    w[i] = __expf(e);
}

__global__ void k_edgew1(const int* __restrict__ col, const int* __restrict__ dstarr,
                         const float* __restrict__ als, const float* __restrict__ ald,
                         float* __restrict__ w, int Etot) {
    int j = blockIdx.x * blockDim.x + threadIdx.x;
    if (j >= Etot) return;
    float e = als[col[j]] + ald[dstarr[j]];
    e = LRELU(e);
    w[j] = __expf(e);
}

// ---------------- single-pass aggregate + fused BN partial stats ----------------
// 64 lanes/node, 4 nodes/block. Epilogue: block-reduce column sums/sumsq into
// 64-slot partial buffer (slot = blockIdx&63) -> low atomic contention.

__global__ __launch_bounds__(256) void k_agg(const int* __restrict__ rowptr,
                                             const int* __restrict__ col,
                                             const short* __restrict__ Hb,
                                             const float* __restrict__ w,
                                             const float* __restrict__ bias,
                                             float* __restrict__ out,
                                             float* __restrict__ part, int N) {
    __shared__ float red[4][128];
    int wv = threadIdx.x >> 6;
    int node = blockIdx.x * 4 + wv;
    int lane = threadIdx.x & 63;
    bool valid = node < N;
    int h = lane >> 3;
    int beg = 0, end = 0;
    if (valid) { beg = rowptr[node]; end = rowptr[node + 1]; }
    const int* Hi = (const int*)Hb;
    float ssum = 0.f, a0 = 0.f, a1 = 0.f;
    int j = beg;
    for (; j + 4 <= end; j += 4) {
        int c0 = col[j], c1 = col[j + 1], c2 = col[j + 2], c3 = col[j + 3];
        float w0 = w[j * 8 + h];
        float w1 = w[(j + 1) * 8 + h];
        float w2 = w[(j + 2) * 8 + h];
        float w3 = w[(j + 3) * 8 + h];
        int p0 = Hi[(c0 << 6) + lane];
        int p1 = Hi[(c1 << 6) + lane];
        int p2 = Hi[(c2 << 6) + lane];
        int p3 = Hi[(c3 << 6) + lane];
        ssum += (w0 + w1) + (w2 + w3);
        a0 += w0 * bflo(p0); a1 += w0 * bfhi(p0);
        a0 += w1 * bflo(p1); a1 += w1 * bfhi(p1);
        a0 += w2 * bflo(p2); a1 += w2 * bfhi(p2);
        a0 += w3 * bflo(p3); a1 += w3 * bfhi(p3);
    }
    for (; j < end; j++) {
        int c = col[j];
        float wv2 = w[j * 8 + h];
        int p = Hi[(c << 6) + lane];
        ssum += wv2;
        a0 += wv2 * bflo(p); a1 += wv2 * bfhi(p);
    }
    float inv = 1.f / (ssum + 1e-16f);
    float2 o = make_float2(0.f, 0.f);
    if (valid) {
        o.x = a0 * inv + bias[2 * lane];
        o.y = a1 * inv + bias[2 * lane + 1];
        ((float2*)out)[(size_t)node * 64 + lane] = o;
    }
    red[wv][2 * lane] = o.x;
    red[wv][2 * lane + 1] = o.y;
    __syncthreads();
    if (threadIdx.x < 128) {
        int c = threadIdx.x;
        float v0 = red[0][c], v1 = red[1][c], v2 = red[2][c], v3 = red[3][c];
        float s = (v0 + v1) + (v2 + v3);
        float q = (v0 * v0 + v1 * v1) + (v2 * v2 + v3 * v3);
        float* slot = part + (blockIdx.x & 63) * 256;
        atomicAdd(&slot[c], s);
        atomicAdd(&slot[128 + c], q);
    }
}

// ---------------- reduce 64-slot partials -> bns[256] ----------------

__global__ __launch_bounds__(256) void k_bnreduce(const float* __restrict__ part,
                                                  float* __restrict__ bns) {
    int c = threadIdx.x;
    float s = 0.f;
    #pragma unroll
    for (int k = 0; k < 64; k++) s += part[k * 256 + c];
    bns[c] = s;
}

// ---------------- BN apply + ReLU + residual ----------------

__global__ void k_bnapply(const float* __restrict__ V, const float* __restrict__ sums,
                          const float* __restrict__ g, const float* __restrict__ bt,
                          const float* __restrict__ xres, float* __restrict__ xout,
                          int N, float invN) {
    int i = blockIdx.x * blockDim.x + threadIdx.x;
    if (i >= N * 32) return;
    int c0 = (i & 31) * 4;
    float4 v = ((const float4*)V)[i];
    float4 xr = ((const float4*)xres)[i];
    float vv[4] = {v.x, v.y, v.z, v.w};
    float xx[4] = {xr.x, xr.y, xr.z, xr.w};
    float oo[4];
    #pragma unroll
    for (int j = 0; j < 4; j++) {
        int c = c0 + j;
        float mu = sums[c] * invN;
        float var = sums[128 + c] * invN - mu * mu;
        float y = (vv[j] - mu) * rsqrtf(var + 1e-5f) * g[c] + bt[c];
        oo[j] = fmaxf(y, 0.f) + xx[j];
    }
    ((float4*)xout)[i] = make_float4(oo[0], oo[1], oo[2], oo[3]);
}

// ---------------- layer-2 logits ----------------

__global__ void k_al2(const short* __restrict__ Hb2, const float* __restrict__ as2,
                      const float* __restrict__ ad2, float* __restrict__ als,
                      float* __restrict__ ald, int N) {
    int node = blockIdx.x * 4 + (threadIdx.x >> 6);
    int lc = threadIdx.x & 63;
    if (node >= N) return;
    float v = bf2f(((const unsigned short*)Hb2)[(size_t)node * 64 + lc]);
    float s = v * as2[lc];
    float d = v * ad2[lc];
    #pragma unroll
    for (int off = 32; off; off >>= 1) {
        s += __shfl_xor(s, off, 64);
        d += __shfl_xor(d, off, 64);
    }
    if (lc == 0) { als[node] = s; ald[node] = d; }
}

// ---------------- layer-2 aggregate + LayerNorm ----------------

__global__ void k_agg2ln(const int* __restrict__ rowptr, const int* __restrict__ col,
                         const short* __restrict__ Hb2, const float* __restrict__ w,
                         const float* __restrict__ b2,
                         const float* __restrict__ lng, const float* __restrict__ lnb,
                         float* __restrict__ out, int N) {
    int node = blockIdx.x * 4 + (threadIdx.x >> 6);
    int lc = threadIdx.x & 63;
    if (node >= N) return;
    const unsigned short* H = (const unsigned short*)Hb2;
    int beg = rowptr[node], end = rowptr[node + 1];
    float ssum = 0.f, acc = 0.f;
    int j = beg;
    for (; j + 4 <= end; j += 4) {
        int c0 = col[j], c1 = col[j + 1], c2 = col[j + 2], c3 = col[j + 3];
        float w0 = w[j], w1 = w[j + 1], w2 = w[j + 2], w3 = w[j + 3];
        float h0 = bf2f(H[(c0 << 6) + lc]);
        float h1 = bf2f(H[(c1 << 6) + lc]);
        float h2 = bf2f(H[(c2 << 6) + lc]);
        float h3 = bf2f(H[(c3 << 6) + lc]);
        ssum += (w0 + w1) + (w2 + w3);
        acc += w0 * h0;
        acc += w1 * h1;
        acc += w2 * h2;
        acc += w3 * h3;
    }
    for (; j < end; j++) {
        int c = col[j];
        float wv = w[j];
        ssum += wv;
        acc += wv * bf2f(H[(c << 6) + lc]);
    }
    float v = acc / (ssum + 1e-16f) + b2[lc];
    float su = v, sq = v * v;
    #pragma unroll
    for (int off = 32; off; off >>= 1) {
        su += __shfl_xor(su, off, 64);
        sq += __shfl_xor(sq, off, 64);
    }
    float mu = su * (1.f / 64.f);
    float var = sq * (1.f / 64.f) - mu * mu;
    float r = rsqrtf(var + 1e-5f);
    out[(size_t)node * 64 + lc] = (v - mu) * r * lng[lc] + lnb[lc];
}

// ---------------- launch ----------------

extern "C" void kernel_launch(void* const* d_in, const int* in_sizes, int n_in,
                              void* d_out, int out_size, void* d_ws, size_t ws_size,
                              hipStream_t stream) {
    const float* x   = (const float*)d_in[0];
    const int*   ei  = (const int*)d_in[1];
    const float* W0  = (const float*)d_in[2];
    const float* as0 = (const float*)d_in[3];
    const float* ad0 = (const float*)d_in[4];
    const float* b0  = (const float*)d_in[5];
    const float* g0  = (const float*)d_in[6];
    const float* bt0 = (const float*)d_in[7];
    const float* W1  = (const float*)d_in[8];
    const float* as1 = (const float*)d_in[9];
    const float* ad1 = (const float*)d_in[10];
    const float* b1  = (const float*)d_in[11];
    const float* g1  = (const float*)d_in[12];
    const float* bt1 = (const float*)d_in[13];
    const float* W2  = (const float*)d_in[14];
    const float* as2 = (const float*)d_in[15];
    const float* ad2 = (const float*)d_in[16];
    const float* b2  = (const float*)d_in[17];
    const float* lng = (const float*)d_in[18];
    const float* lnb = (const float*)d_in[19];

    const int N = in_sizes[0] / 128;
    const int E = in_sizes[1] / 2;
    const int Etot = E + N;

    char* p = (char*)d_ws;
    auto carve = [&](size_t bytes) {
        void* q = (void*)p;
        p += (bytes + 255) & ~(size_t)255;
        return q;
    };
    short* Hb     = (short*)carve((size_t)N * 128 * 2);
    float* agg    = (float*)carve((size_t)N * 128 * 4);
    float* x1     = (float*)carve((size_t)N * 128 * 4);
    float* als    = (float*)carve((size_t)N * 8 * 4);
    float* ald    = (float*)carve((size_t)N * 8 * 4);
    int*   rowptr = (int*)carve((size_t)(N + 1) * 4);
    int*   cursor = (int*)carve((size_t)(N + 1) * 4);
    int*   deg    = (int*)carve((size_t)N * 4);
    int*   col    = (int*)carve((size_t)Etot * 4);
    int*   dstarr = (int*)carve((size_t)Etot * 4);
    float* w      = (float*)carve((size_t)Etot * 8 * 4);
    float* bns    = (float*)carve(256 * 4);
    float* part   = (float*)carve(64 * 256 * 4);
    short* Wt0    = (short*)carve(128 * 128 * 2);
    short* Wt1    = (short*)carve(128 * 128 * 2);
    short* Wt2    = (short*)carve(64 * 128 * 2);
    int*   partial= (int*)carve(256 * 4);

    const float invN = 1.f / (float)N;
    const int eb = (E + N + 255) / 256;
    const int nsb = (N + SC - 1) / SC;

    k_wprep<<<(128 * 128 + 64 * 128 + 255) / 256, 256, 0, stream>>>(W0, W1, W2, Wt0, Wt1, Wt2);

    // CSR build
    hipMemsetAsync(deg, 0, (size_t)N * 4, stream);
    k_count<<<eb, 256, 0, stream>>>(ei + E, E, N, deg);
    k_scan1<<<nsb, 256, 0, stream>>>(deg, N, partial);
    k_scan2<<<1, 256, 0, stream>>>(partial, nsb);
    k_scan3<<<nsb, 256, 0, stream>>>(deg, N, Etot, partial, rowptr, cursor);
    k_fill<<<eb, 256, 0, stream>>>(ei, ei + E, E, N, cursor, col, dstarr);

    const int gb = (N + 127) / 128;
    const int ewb8 = (Etot * 8 + 255) / 256;
    const int ewb1 = (Etot + 255) / 256;
    const int ab = (N + 3) / 4;

    // ---- layer 0 ----
    k_gemm<128><<<gb, 256, 0, stream>>>(x, Wt0, Hb, N);
    k_al<<<(N * 8 + 255) / 256, 256, 0, stream>>>(Hb, as0, ad0, als, ald, N);
    k_edgew8<<<ewb8, 256, 0, stream>>>(col, dstarr, als, ald, w, Etot);
    hipMemsetAsync(part, 0, 64 * 256 * 4, stream);
    k_agg<<<ab, 256, 0, stream>>>(rowptr, col, Hb, w, b0, agg, part, N);
    k_bnreduce<<<1, 256, 0, stream>>>(part, bns);
    k_bnapply<<<(N * 32 + 255) / 256, 256, 0, stream>>>(agg, bns, g0, bt0, x, x1, N, invN);

    // ---- layer 1 ----
    k_gemm<128><<<gb, 256, 0, stream>>>(x1, Wt1, Hb, N);
    k_al<<<(N * 8 + 255) / 256, 256, 0, stream>>>(Hb, as1, ad1, als, ald, N);
    k_edgew8<<<ewb8, 256, 0, stream>>>(col, dstarr, als, ald, w, Etot);
    hipMemsetAsync(part, 0, 64 * 256 * 4, stream);
    k_agg<<<ab, 256, 0, stream>>>(rowptr, col, Hb, w, b1, agg, part, N);
    k_bnreduce<<<1, 256, 0, stream>>>(part, bns);
    k_bnapply<<<(N * 32 + 255) / 256, 256, 0, stream>>>(agg, bns, g1, bt1, x1, x1, N, invN);

    // ---- layer 2 + LayerNorm ----
    k_gemm<64><<<gb, 256, 0, stream>>>(x1, Wt2, Hb, N);
    k_al2<<<(N + 3) / 4, 256, 0, stream>>>(Hb, as2, ad2, als, ald, N);
    k_edgew1<<<ewb1, 256, 0, stream>>>(col, dstarr, als, ald, w, Etot);
    k_agg2ln<<<(N + 3) / 4, 256, 0, stream>>>(rowptr, col, Hb, w, b2, lng, lnb,
                                              (float*)d_out, N);
}

// Round 6
// 553.846 us; speedup vs baseline: 2.6288x; 1.0495x over previous
//
#include <hip/hip_runtime.h>
#include <hip/hip_bf16.h>

#define LRELU(e) ((e) > 0.f ? (e) : 0.2f * (e))

typedef __attribute__((ext_vector_type(8))) short bf16x8;
typedef __attribute__((ext_vector_type(4))) float floatx4;

__device__ inline short f2bf(float f) {
    union { float f; unsigned u; } v; v.f = f;
    unsigned r = v.u + 0x7fffu + ((v.u >> 16) & 1u);
    return (short)(r >> 16);
}
__device__ inline float bflo(int p) {
    union { unsigned u; float f; } v; v.u = (unsigned)p << 16; return v.f;
}
__device__ inline float bfhi(int p) {
    union { unsigned u; float f; } v; v.u = (unsigned)p & 0xffff0000u; return v.f;
}
__device__ inline float bf2f(unsigned short s) {
    union { unsigned u; float f; } v; v.u = (unsigned)s << 16; return v.f;
}

// ---------------- CSR build ----------------

__global__ void k_count(const int* __restrict__ dstE, int E, int N, int* __restrict__ deg) {
    int i = blockIdx.x * blockDim.x + threadIdx.x;
    if (i < E) atomicAdd(&deg[dstE[i]], 1);
    else if (i < E + N) atomicAdd(&deg[i - E], 1);
}

constexpr int SC = 2048;

__global__ __launch_bounds__(256) void k_scan1(const int* __restrict__ deg, int N,
                                               int* __restrict__ partial) {
    int base = blockIdx.x * SC;
    int t = threadIdx.x;
    int s = 0;
    #pragma unroll
    for (int p = 0; p < SC / 256; p++) {
        int i = base + t + p * 256;
        if (i < N) s += deg[i];
    }
    #pragma unroll
    for (int off = 32; off; off >>= 1) s += __shfl_xor(s, off, 64);
    __shared__ int ws[4];
    int lane = t & 63, wid = t >> 6;
    if (lane == 0) ws[wid] = s;
    __syncthreads();
    if (t == 0) partial[blockIdx.x] = ws[0] + ws[1] + ws[2] + ws[3];
}

__global__ __launch_bounds__(256) void k_scan2(int* __restrict__ partial, int nb) {
    int t = threadIdx.x;
    int v = (t < nb) ? partial[t] : 0;
    int lane = t & 63, wid = t >> 6;
    int x = v;
    #pragma unroll
    for (int off = 1; off < 64; off <<= 1) {
        int y = __shfl_up(x, off, 64);
        if (lane >= off) x += y;
    }
    __shared__ int wsum[4];
    if (lane == 63) wsum[wid] = x;
    __syncthreads();
    int add = 0;
    for (int i = 0; i < wid; i++) add += wsum[i];
    if (t < nb) partial[t] = x + add - v;
}

__global__ __launch_bounds__(256) void k_scan3(const int* __restrict__ deg, int N, int Etot,
                                               const int* __restrict__ partial,
                                               int* __restrict__ rowptr,
                                               int* __restrict__ cursor) {
    int base = blockIdx.x * SC;
    int t = threadIdx.x;
    int i0 = base + t * 8;
    int v[8];
    int s = 0;
    #pragma unroll
    for (int p = 0; p < 8; p++) {
        int i = i0 + p;
        v[p] = (i < N) ? deg[i] : 0;
        s += v[p];
    }
    int lane = t & 63, wid = t >> 6;
    int x = s;
    #pragma unroll
    for (int off = 1; off < 64; off <<= 1) {
        int y = __shfl_up(x, off, 64);
        if (lane >= off) x += y;
    }
    __shared__ int wsum[4];
    if (lane == 63) wsum[wid] = x;
    __syncthreads();
    int add = 0;
    for (int i = 0; i < wid; i++) add += wsum[i];
    int excl = x - s + add + partial[blockIdx.x];
    #pragma unroll
    for (int p = 0; p < 8; p++) {
        int i = i0 + p;
        if (i < N) { rowptr[i] = excl; cursor[i] = excl; }
        excl += v[p];
    }
    if (blockIdx.x == 0 && t == 0) rowptr[N] = Etot;
}

__global__ void k_fill(const int* __restrict__ srcE, const int* __restrict__ dstE,
                       int E, int N, int* __restrict__ cursor, int* __restrict__ col) {
    int i = blockIdx.x * blockDim.x + threadIdx.x;
    if (i < E) {
        int d = dstE[i];
        int p = atomicAdd(&cursor[d], 1);
        col[p] = srcE[i];
    } else if (i < E + N) {
        int d = i - E;
        int p = atomicAdd(&cursor[d], 1);
        col[p] = d;
    }
}

// ---------------- W prep ----------------

__global__ void k_wprep(const float* __restrict__ W0, const float* __restrict__ W1,
                        const float* __restrict__ W2, short* __restrict__ Wt0,
                        short* __restrict__ Wt1, short* __restrict__ Wt2) {
    int i = blockIdx.x * blockDim.x + threadIdx.x;
    if (i < 128 * 128) {
        int n = i >> 7, k = i & 127;
        Wt0[i] = f2bf(W0[k * 128 + n]);
        Wt1[i] = f2bf(W1[k * 128 + n]);
    } else {
        i -= 128 * 128;
        if (i < 64 * 128) {
            int n = i >> 7, k = i & 127;
            Wt2[i] = f2bf(W2[k * 64 + n]);
        }
    }
}

// ---------------- MFMA bf16 GEMM, optional fused BN-apply+ReLU+residual ----------------
// HASBN: X is pre-BN 'agg'; y = relu(X*scale+shift) + Xres is the real GEMM input.
// WRITEX: store y (fp32) to Xout for use as the next layer's residual.

template <int DOUT, bool HASBN, bool WRITEX>
__global__ __launch_bounds__(256) void k_gemm(const float* __restrict__ X,
                                              const short* __restrict__ Wt,
                                              short* __restrict__ Hout,
                                              const float2* __restrict__ ss,
                                              const float* __restrict__ Xres,
                                              float* __restrict__ Xout, int Nrows) {
    constexpr int KP = 136;
    constexpr int CT = DOUT / 16;
    __shared__ __align__(16) short Xs[128 * KP];
    __shared__ __align__(16) short Ws[DOUT * KP];

    const int tid = threadIdx.x;
    const int row0 = blockIdx.x * 128;

    {
        int c4 = tid & 31;
        int r0 = tid >> 5;
        float2 ssv[4];
        if (HASBN) {
            #pragma unroll
            for (int j = 0; j < 4; j++) ssv[j] = ss[c4 * 4 + j];
        }
        #pragma unroll
        for (int p = 0; p < 16; p++) {
            int r = r0 + p * 8;
            int grow = row0 + r;
            float4 v = make_float4(0.f, 0.f, 0.f, 0.f);
            float4 xr = make_float4(0.f, 0.f, 0.f, 0.f);
            if (grow < Nrows) {
                v = *(const float4*)&X[(size_t)grow * 128 + c4 * 4];
                if (HASBN) xr = *(const float4*)&Xres[(size_t)grow * 128 + c4 * 4];
            }
            if (HASBN) {
                float* vp = (float*)&v;
                float* xp = (float*)&xr;
                #pragma unroll
                for (int j = 0; j < 4; j++)
                    vp[j] = fmaxf(vp[j] * ssv[j].x + ssv[j].y, 0.f) + xp[j];
                if (WRITEX && grow < Nrows)
                    *(float4*)&Xout[(size_t)grow * 128 + c4 * 4] = v;
            }
            short4 b;
            b.x = f2bf(v.x); b.y = f2bf(v.y); b.z = f2bf(v.z); b.w = f2bf(v.w);
            *(short4*)&Xs[r * KP + c4 * 4] = b;
        }
    }
    {
        constexpr int UNITS = DOUT * 16;
        #pragma unroll
        for (int p = 0; p < UNITS / 256; p++) {
            int u = tid + p * 256;
            int n = u >> 4;
            int kc = (u & 15) * 8;
            bf16x8 v = *(const bf16x8*)&Wt[n * 128 + kc];
            *(bf16x8*)&Ws[n * KP + kc] = v;
        }
    }
    __syncthreads();

    const int lane = tid & 63;
    const int wv = tid >> 6;
    const int m0 = wv * 32;
    const int ln = lane & 15;
    const int quad = lane >> 4;

    floatx4 acc[2][CT];
    #pragma unroll
    for (int mt = 0; mt < 2; mt++)
        #pragma unroll
        for (int ct = 0; ct < CT; ct++) acc[mt][ct] = (floatx4){0.f, 0.f, 0.f, 0.f};

    #pragma unroll
    for (int ks = 0; ks < 4; ks++) {
        int ko = ks * 32 + quad * 8;
        bf16x8 a0 = *(const bf16x8*)&Xs[(m0 + ln) * KP + ko];
        bf16x8 a1 = *(const bf16x8*)&Xs[(m0 + 16 + ln) * KP + ko];
        #pragma unroll
        for (int ct = 0; ct < CT; ct++) {
            bf16x8 b = *(const bf16x8*)&Ws[(ct * 16 + ln) * KP + ko];
            acc[0][ct] = __builtin_amdgcn_mfma_f32_16x16x32_bf16(a0, b, acc[0][ct], 0, 0, 0);
            acc[1][ct] = __builtin_amdgcn_mfma_f32_16x16x32_bf16(a1, b, acc[1][ct], 0, 0, 0);
        }
    }

    #pragma unroll
    for (int mt = 0; mt < 2; mt++) {
        #pragma unroll
        for (int r = 0; r < 4; r++) {
            int grow = row0 + m0 + mt * 16 + quad * 4 + r;
            if (grow < Nrows) {
                #pragma unroll
                for (int ct = 0; ct < CT; ct++)
                    Hout[(size_t)grow * DOUT + ct * 16 + ln] = f2bf(acc[mt][ct][r]);
            }
        }
    }
}

// ---------------- attention logits (8 heads x 16), bf16 H ----------------

__global__ void k_al(const short* __restrict__ Hb, const float* __restrict__ a_s,
                     const float* __restrict__ a_d, float* __restrict__ als,
                     float* __restrict__ ald, int N) {
    int i = blockIdx.x * blockDim.x + threadIdx.x;
    if (i >= N * 8) return;
    int n = i >> 3, h = i & 7;
    const int4* hp = (const int4*)(Hb + (size_t)n * 128 + h * 16);
    int4 q0 = hp[0], q1 = hp[1];
    float hv[16] = {bflo(q0.x), bfhi(q0.x), bflo(q0.y), bfhi(q0.y),
                    bflo(q0.z), bfhi(q0.z), bflo(q0.w), bfhi(q0.w),
                    bflo(q1.x), bfhi(q1.x), bflo(q1.y), bfhi(q1.y),
                    bflo(q1.z), bfhi(q1.z), bflo(q1.w), bfhi(q1.w)};
    const float* sp = a_s + h * 16;
    const float* dp = a_d + h * 16;
    float ss = 0.f, sd = 0.f;
    #pragma unroll
    for (int j = 0; j < 16; j++) {
        ss += hv[j] * sp[j];
        sd += hv[j] * dp[j];
    }
    als[i] = ss;
    ald[i] = sd;
}

// ---------------- aggregate: fused edge weights + softmax-normalize + BN stats ----------
// 64 lanes/node, 4 nodes/block. Per edge: e=lrelu(als[c*8+h]+ald[d*8+h]); w=exp(e).
// als is 3.2 MB -> L2-resident gathers.

__global__ __launch_bounds__(256) void k_agg(const int* __restrict__ rowptr,
                                             const int* __restrict__ col,
                                             const short* __restrict__ Hb,
                                             const float* __restrict__ als,
                                             const float* __restrict__ ald,
                                             const float* __restrict__ bias,
                                             float* __restrict__ out,
                                             float* __restrict__ part, int N) {
    __shared__ float red[4][128];
    int wv = threadIdx.x >> 6;
    int node = blockIdx.x * 4 + wv;
    int lane = threadIdx.x & 63;
    bool valid = node < N;
    int h = lane >> 3;
    int beg = 0, end = 0;
    float aldv = 0.f;
    if (valid) { beg = rowptr[node]; end = rowptr[node + 1]; aldv = ald[node * 8 + h]; }
    const int* Hi = (const int*)Hb;
    float ssum = 0.f, a0 = 0.f, a1 = 0.f;
    int j = beg;
    for (; j + 8 <= end; j += 8) {
        int cc[8];
        #pragma unroll
        for (int k = 0; k < 8; k++) cc[k] = col[j + k];
        float ee[8];
        int pp[8];
        #pragma unroll
        for (int k = 0; k < 8; k++) {
            ee[k] = als[cc[k] * 8 + h];
            pp[k] = Hi[(cc[k] << 6) + lane];
        }
        #pragma unroll
        for (int k = 0; k < 8; k++) {
            float e = ee[k] + aldv;
            e = LRELU(e);
            float wv2 = __expf(e);
            ssum += wv2;
            a0 += wv2 * bflo(pp[k]);
            a1 += wv2 * bfhi(pp[k]);
        }
    }
    for (; j < end; j++) {
        int c = col[j];
        float e = als[c * 8 + h] + aldv;
        e = LRELU(e);
        float wv2 = __expf(e);
        int p = Hi[(c << 6) + lane];
        ssum += wv2;
        a0 += wv2 * bflo(p);
        a1 += wv2 * bfhi(p);
    }
    float inv = 1.f / (ssum + 1e-16f);
    float2 o = make_float2(0.f, 0.f);
    if (valid) {
        o.x = a0 * inv + bias[2 * lane];
        o.y = a1 * inv + bias[2 * lane + 1];
        ((float2*)out)[(size_t)node * 64 + lane] = o;
    }
    red[wv][2 * lane] = o.x;
    red[wv][2 * lane + 1] = o.y;
    __syncthreads();
    if (threadIdx.x < 128) {
        int c = threadIdx.x;
        float v0 = red[0][c], v1 = red[1][c], v2 = red[2][c], v3 = red[3][c];
        float s = (v0 + v1) + (v2 + v3);
        float q = (v0 * v0 + v1 * v1) + (v2 * v2 + v3 * v3);
        float* slot = part + (blockIdx.x & 63) * 256;
        atomicAdd(&slot[c], s);
        atomicAdd(&slot[128 + c], q);
    }
}

// ---------------- reduce partials -> per-column (scale, shift) ----------------

__global__ __launch_bounds__(128) void k_bnreduce(const float* __restrict__ part,
                                                  const float* __restrict__ g,
                                                  const float* __restrict__ bt,
                                                  float invN, float2* __restrict__ ss) {
    int c = threadIdx.x;   // 0..127
    float s = 0.f, q = 0.f;
    #pragma unroll
    for (int k = 0; k < 64; k++) {
        s += part[k * 256 + c];
        q += part[k * 256 + 128 + c];
    }
    float mu = s * invN;
    float var = q * invN - mu * mu;
    float scale = rsqrtf(var + 1e-5f) * g[c];
    ss[c] = make_float2(scale, bt[c] - mu * scale);
}

// ---------------- layer-2 logits ----------------

__global__ void k_al2(const short* __restrict__ Hb2, const float* __restrict__ as2,
                      const float* __restrict__ ad2, float* __restrict__ als,
                      float* __restrict__ ald, int N) {
    int node = blockIdx.x * 4 + (threadIdx.x >> 6);
    int lc = threadIdx.x & 63;
    if (node >= N) return;
    float v = bf2f(((const unsigned short*)Hb2)[(size_t)node * 64 + lc]);
    float s = v * as2[lc];
    float d = v * ad2[lc];
    #pragma unroll
    for (int off = 32; off; off >>= 1) {
        s += __shfl_xor(s, off, 64);
        d += __shfl_xor(d, off, 64);
    }
    if (lc == 0) { als[node] = s; ald[node] = d; }
}

// ---------------- layer-2: fused edge weights + aggregate + LayerNorm ----------------

__global__ void k_agg2ln(const int* __restrict__ rowptr, const int* __restrict__ col,
                         const short* __restrict__ Hb2, const float* __restrict__ als,
                         const float* __restrict__ ald, const float* __restrict__ b2,
                         const float* __restrict__ lng, const float* __restrict__ lnb,
                         float* __restrict__ out, int N) {
    int node = blockIdx.x * 4 + (threadIdx.x >> 6);
    int lc = threadIdx.x & 63;
    if (node >= N) return;
    const unsigned short* H = (const unsigned short*)Hb2;
    int beg = rowptr[node], end = rowptr[node + 1];
    float aldv = ald[node];
    float ssum = 0.f, acc = 0.f;
    int j = beg;
    for (; j + 8 <= end; j += 8) {
        int cc[8];
        #pragma unroll
        for (int k = 0; k < 8; k++) cc[k] = col[j + k];
        float ee[8];
        unsigned short pp[8];
        #pragma unroll
        for (int k = 0; k < 8; k++) {
            ee[k] = als[cc[k]];
            pp[k] = H[(cc[k] << 6) + lc];
        }
        #pragma unroll
        for (int k = 0; k < 8; k++) {
            float e = ee[k] + aldv;
            e = LRELU(e);
            float wv = __expf(e);
            ssum += wv;
            acc += wv * bf2f(pp[k]);
        }
    }
    for (; j < end; j++) {
        int c = col[j];
        float e = als[c] + aldv;
        e = LRELU(e);
        float wv = __expf(e);
        ssum += wv;
        acc += wv * bf2f(H[(c << 6) + lc]);
    }
    float v = acc / (ssum + 1e-16f) + b2[lc];
    float su = v, sq = v * v;
    #pragma unroll
    for (int off = 32; off; off >>= 1) {
        su += __shfl_xor(su, off, 64);
        sq += __shfl_xor(sq, off, 64);
    }
    float mu = su * (1.f / 64.f);
    float var = sq * (1.f / 64.f) - mu * mu;
    float r = rsqrtf(var + 1e-5f);
    out[(size_t)node * 64 + lc] = (v - mu) * r * lng[lc] + lnb[lc];
}

// ---------------- launch ----------------

extern "C" void kernel_launch(void* const* d_in, const int* in_sizes, int n_in,
                              void* d_out, int out_size, void* d_ws, size_t ws_size,
                              hipStream_t stream) {
    const float* x   = (const float*)d_in[0];
    const int*   ei  = (const int*)d_in[1];
    const float* W0  = (const float*)d_in[2];
    const float* as0 = (const float*)d_in[3];
    const float* ad0 = (const float*)d_in[4];
    const float* b0  = (const float*)d_in[5];
    const float* g0  = (const float*)d_in[6];
    const float* bt0 = (const float*)d_in[7];
    const float* W1  = (const float*)d_in[8];
    const float* as1 = (const float*)d_in[9];
    const float* ad1 = (const float*)d_in[10];
    const float* b1  = (const float*)d_in[11];
    const float* g1  = (const float*)d_in[12];
    const float* bt1 = (const float*)d_in[13];
    const float* W2  = (const float*)d_in[14];
    const float* as2 = (const float*)d_in[15];
    const float* ad2 = (const float*)d_in[16];
    const float* b2  = (const float*)d_in[17];
    const float* lng = (const float*)d_in[18];
    const float* lnb = (const float*)d_in[19];

    const int N = in_sizes[0] / 128;
    const int E = in_sizes[1] / 2;
    const int Etot = E + N;

    char* p = (char*)d_ws;
    auto carve = [&](size_t bytes) {
        void* q = (void*)p;
        p += (bytes + 255) & ~(size_t)255;
        return q;
    };
    short* Hb     = (short*)carve((size_t)N * 128 * 2);
    float* agg    = (float*)carve((size_t)N * 128 * 4);
    float* x1     = (float*)carve((size_t)N * 128 * 4);
    float* als    = (float*)carve((size_t)N * 8 * 4);
    float* ald    = (float*)carve((size_t)N * 8 * 4);
    int*   rowptr = (int*)carve((size_t)(N + 1) * 4);
    int*   cursor = (int*)carve((size_t)(N + 1) * 4);
    int*   deg    = (int*)carve((size_t)N * 4);
    int*   col    = (int*)carve((size_t)Etot * 4);
    float* part   = (float*)carve(64 * 256 * 4);
    float2* ss    = (float2*)carve(128 * 8);
    short* Wt0    = (short*)carve(128 * 128 * 2);
    short* Wt1    = (short*)carve(128 * 128 * 2);
    short* Wt2    = (short*)carve(64 * 128 * 2);
    int*   partial= (int*)carve(256 * 4);

    const float invN = 1.f / (float)N;
    const int eb = (E + N + 255) / 256;
    const int nsb = (N + SC - 1) / SC;

    k_wprep<<<(128 * 128 + 64 * 128 + 255) / 256, 256, 0, stream>>>(W0, W1, W2, Wt0, Wt1, Wt2);

    // CSR build
    hipMemsetAsync(deg, 0, (size_t)N * 4, stream);
    k_count<<<eb, 256, 0, stream>>>(ei + E, E, N, deg);
    k_scan1<<<nsb, 256, 0, stream>>>(deg, N, partial);
    k_scan2<<<1, 256, 0, stream>>>(partial, nsb);
    k_scan3<<<nsb, 256, 0, stream>>>(deg, N, Etot, partial, rowptr, cursor);
    k_fill<<<eb, 256, 0, stream>>>(ei, ei + E, E, N, cursor, col);

    const int gb = (N + 127) / 128;
    const int ab = (N + 3) / 4;

    // ---- layer 0 ----
    k_gemm<128, false, false><<<gb, 256, 0, stream>>>(x, Wt0, Hb, nullptr, nullptr, nullptr, N);
    k_al<<<(N * 8 + 255) / 256, 256, 0, stream>>>(Hb, as0, ad0, als, ald, N);
    hipMemsetAsync(part, 0, 64 * 256 * 4, stream);
    k_agg<<<ab, 256, 0, stream>>>(rowptr, col, Hb, als, ald, b0, agg, part, N);
    k_bnreduce<<<1, 128, 0, stream>>>(part, g0, bt0, invN, ss);

    // ---- layer 1 (BN-apply of layer 0 fused into GEMM staging) ----
    k_gemm<128, true, true><<<gb, 256, 0, stream>>>(agg, Wt1, Hb, ss, x, x1, N);
    k_al<<<(N * 8 + 255) / 256, 256, 0, stream>>>(Hb, as1, ad1, als, ald, N);
    hipMemsetAsync(part, 0, 64 * 256 * 4, stream);
    k_agg<<<ab, 256, 0, stream>>>(rowptr, col, Hb, als, ald, b1, agg, part, N);
    k_bnreduce<<<1, 128, 0, stream>>>(part, g1, bt1, invN, ss);

    // ---- layer 2 (BN-apply of layer 1 fused into GEMM staging; x2 never materialized) ----
    k_gemm<64, true, false><<<gb, 256, 0, stream>>>(agg, Wt2, Hb, ss, x1, nullptr, N);
    k_al2<<<(N + 3) / 4, 256, 0, stream>>>(Hb, as2, ad2, als, ald, N);
    k_agg2ln<<<(N + 3) / 4, 256, 0, stream>>>(rowptr, col, Hb, als, ald, b2, lng, lnb,
                                              (float*)d_out, N);
}

// Round 7
// 543.199 us; speedup vs baseline: 2.6803x; 1.0196x over previous
//
#include <hip/hip_runtime.h>
#include <hip/hip_bf16.h>

#define LRELU(e) ((e) > 0.f ? (e) : 0.2f * (e))

typedef __attribute__((ext_vector_type(8))) short bf16x8;
typedef __attribute__((ext_vector_type(4))) float floatx4;

__device__ inline short f2bf(float f) {
    union { float f; unsigned u; } v; v.f = f;
    unsigned r = v.u + 0x7fffu + ((v.u >> 16) & 1u);
    return (short)(r >> 16);
}
__device__ inline float bflo(int p) {
    union { unsigned u; float f; } v; v.u = (unsigned)p << 16; return v.f;
}
__device__ inline float bfhi(int p) {
    union { unsigned u; float f; } v; v.u = (unsigned)p & 0xffff0000u; return v.f;
}
__device__ inline float bf2f(unsigned short s) {
    union { unsigned u; float f; } v; v.u = (unsigned)s << 16; return v.f;
}

// ---------------- CSR build ----------------

__global__ void k_count(const int* __restrict__ dstE, int E, int N, int* __restrict__ deg) {
    int i = blockIdx.x * blockDim.x + threadIdx.x;
    if (i < E) atomicAdd(&deg[dstE[i]], 1);
    else if (i < E + N) atomicAdd(&deg[i - E], 1);
}

constexpr int SC = 2048;

__global__ __launch_bounds__(256) void k_scan1(const int* __restrict__ deg, int N,
                                               int* __restrict__ partial) {
    int base = blockIdx.x * SC;
    int t = threadIdx.x;
    int s = 0;
    #pragma unroll
    for (int p = 0; p < SC / 256; p++) {
        int i = base + t + p * 256;
        if (i < N) s += deg[i];
    }
    #pragma unroll
    for (int off = 32; off; off >>= 1) s += __shfl_xor(s, off, 64);
    __shared__ int ws[4];
    int lane = t & 63, wid = t >> 6;
    if (lane == 0) ws[wid] = s;
    __syncthreads();
    if (t == 0) partial[blockIdx.x] = ws[0] + ws[1] + ws[2] + ws[3];
}

__global__ __launch_bounds__(256) void k_scan2(int* __restrict__ partial, int nb) {
    int t = threadIdx.x;
    int v = (t < nb) ? partial[t] : 0;
    int lane = t & 63, wid = t >> 6;
    int x = v;
    #pragma unroll
    for (int off = 1; off < 64; off <<= 1) {
        int y = __shfl_up(x, off, 64);
        if (lane >= off) x += y;
    }
    __shared__ int wsum[4];
    if (lane == 63) wsum[wid] = x;
    __syncthreads();
    int add = 0;
    for (int i = 0; i < wid; i++) add += wsum[i];
    if (t < nb) partial[t] = x + add - v;
}

__global__ __launch_bounds__(256) void k_scan3(const int* __restrict__ deg, int N, int Etot,
                                               const int* __restrict__ partial,
                                               int* __restrict__ rowptr,
                                               int* __restrict__ cursor) {
    int base = blockIdx.x * SC;
    int t = threadIdx.x;
    int i0 = base + t * 8;
    int v[8];
    int s = 0;
    #pragma unroll
    for (int p = 0; p < 8; p++) {
        int i = i0 + p;
        v[p] = (i < N) ? deg[i] : 0;
        s += v[p];
    }
    int lane = t & 63, wid = t >> 6;
    int x = s;
    #pragma unroll
    for (int off = 1; off < 64; off <<= 1) {
        int y = __shfl_up(x, off, 64);
        if (lane >= off) x += y;
    }
    __shared__ int wsum[4];
    if (lane == 63) wsum[wid] = x;
    __syncthreads();
    int add = 0;
    for (int i = 0; i < wid; i++) add += wsum[i];
    int excl = x - s + add + partial[blockIdx.x];
    #pragma unroll
    for (int p = 0; p < 8; p++) {
        int i = i0 + p;
        if (i < N) { rowptr[i] = excl; cursor[i] = excl; }
        excl += v[p];
    }
    if (blockIdx.x == 0 && t == 0) rowptr[N] = Etot;
}

__global__ void k_fill(const int* __restrict__ srcE, const int* __restrict__ dstE,
                       int E, int N, int* __restrict__ cursor, int* __restrict__ col,
                       int* __restrict__ dstarr) {
    int i = blockIdx.x * blockDim.x + threadIdx.x;
    if (i < E) {
        int d = dstE[i];
        int p = atomicAdd(&cursor[d], 1);
        col[p] = srcE[i];
        dstarr[p] = d;
    } else if (i < E + N) {
        int d = i - E;
        int p = atomicAdd(&cursor[d], 1);
        col[p] = d;
        dstarr[p] = d;
    }
}

// ---------------- W prep ----------------

__global__ void k_wprep(const float* __restrict__ W0, const float* __restrict__ W1,
                        const float* __restrict__ W2, short* __restrict__ Wt0,
                        short* __restrict__ Wt1, short* __restrict__ Wt2) {
    int i = blockIdx.x * blockDim.x + threadIdx.x;
    if (i < 128 * 128) {
        int n = i >> 7, k = i & 127;
        Wt0[i] = f2bf(W0[k * 128 + n]);
        Wt1[i] = f2bf(W1[k * 128 + n]);
    } else {
        i -= 128 * 128;
        if (i < 64 * 128) {
            int n = i >> 7, k = i & 127;
            Wt2[i] = f2bf(W2[k * 64 + n]);
        }
    }
}

// ---------------- MFMA bf16 GEMM, optional fused BN-apply+ReLU+residual ----------------

template <int DOUT, bool HASBN, bool WRITEX>
__global__ __launch_bounds__(256) void k_gemm(const float* __restrict__ X,
                                              const short* __restrict__ Wt,
                                              short* __restrict__ Hout,
                                              const float2* __restrict__ ss,
                                              const float* __restrict__ Xres,
                                              float* __restrict__ Xout, int Nrows) {
    constexpr int KP = 136;
    constexpr int CT = DOUT / 16;
    __shared__ __align__(16) short Xs[128 * KP];
    __shared__ __align__(16) short Ws[DOUT * KP];

    const int tid = threadIdx.x;
    const int row0 = blockIdx.x * 128;

    {
        int c4 = tid & 31;
        int r0 = tid >> 5;
        float2 ssv[4];
        if (HASBN) {
            #pragma unroll
            for (int j = 0; j < 4; j++) ssv[j] = ss[c4 * 4 + j];
        }
        #pragma unroll
        for (int p = 0; p < 16; p++) {
            int r = r0 + p * 8;
            int grow = row0 + r;
            float4 v = make_float4(0.f, 0.f, 0.f, 0.f);
            float4 xr = make_float4(0.f, 0.f, 0.f, 0.f);
            if (grow < Nrows) {
                v = *(const float4*)&X[(size_t)grow * 128 + c4 * 4];
                if (HASBN) xr = *(const float4*)&Xres[(size_t)grow * 128 + c4 * 4];
            }
            if (HASBN) {
                float* vp = (float*)&v;
                float* xp = (float*)&xr;
                #pragma unroll
                for (int j = 0; j < 4; j++)
                    vp[j] = fmaxf(vp[j] * ssv[j].x + ssv[j].y, 0.f) + xp[j];
                if (WRITEX && grow < Nrows)
                    *(float4*)&Xout[(size_t)grow * 128 + c4 * 4] = v;
            }
            short4 b;
            b.x = f2bf(v.x); b.y = f2bf(v.y); b.z = f2bf(v.z); b.w = f2bf(v.w);
            *(short4*)&Xs[r * KP + c4 * 4] = b;
        }
    }
    {
        constexpr int UNITS = DOUT * 16;
        #pragma unroll
        for (int p = 0; p < UNITS / 256; p++) {
            int u = tid + p * 256;
            int n = u >> 4;
            int kc = (u & 15) * 8;
            bf16x8 v = *(const bf16x8*)&Wt[n * 128 + kc];
            *(bf16x8*)&Ws[n * KP + kc] = v;
        }
    }
    __syncthreads();

    const int lane = tid & 63;
    const int wv = tid >> 6;
    const int m0 = wv * 32;
    const int ln = lane & 15;
    const int quad = lane >> 4;

    floatx4 acc[2][CT];
    #pragma unroll
    for (int mt = 0; mt < 2; mt++)
        #pragma unroll
        for (int ct = 0; ct < CT; ct++) acc[mt][ct] = (floatx4){0.f, 0.f, 0.f, 0.f};

    #pragma unroll
    for (int ks = 0; ks < 4; ks++) {
        int ko = ks * 32 + quad * 8;
        bf16x8 a0 = *(const bf16x8*)&Xs[(m0 + ln) * KP + ko];
        bf16x8 a1 = *(const bf16x8*)&Xs[(m0 + 16 + ln) * KP + ko];
        #pragma unroll
        for (int ct = 0; ct < CT; ct++) {
            bf16x8 b = *(const bf16x8*)&Ws[(ct * 16 + ln) * KP + ko];
            acc[0][ct] = __builtin_amdgcn_mfma_f32_16x16x32_bf16(a0, b, acc[0][ct], 0, 0, 0);
            acc[1][ct] = __builtin_amdgcn_mfma_f32_16x16x32_bf16(a1, b, acc[1][ct], 0, 0, 0);
        }
    }

    #pragma unroll
    for (int mt = 0; mt < 2; mt++) {
        #pragma unroll
        for (int r = 0; r < 4; r++) {
            int grow = row0 + m0 + mt * 16 + quad * 4 + r;
            if (grow < Nrows) {
                #pragma unroll
                for (int ct = 0; ct < CT; ct++)
                    Hout[(size_t)grow * DOUT + ct * 16 + ln] = f2bf(acc[mt][ct][r]);
            }
        }
    }
}

// ---------------- attention logits (8 heads x 16), bf16 H ----------------

__global__ void k_al(const short* __restrict__ Hb, const float* __restrict__ a_s,
                     const float* __restrict__ a_d, float* __restrict__ als,
                     float* __restrict__ ald, int N) {
    int i = blockIdx.x * blockDim.x + threadIdx.x;
    if (i >= N * 8) return;
    int n = i >> 3, h = i & 7;
    const int4* hp = (const int4*)(Hb + (size_t)n * 128 + h * 16);
    int4 q0 = hp[0], q1 = hp[1];
    float hv[16] = {bflo(q0.x), bfhi(q0.x), bflo(q0.y), bfhi(q0.y),
                    bflo(q0.z), bfhi(q0.z), bflo(q0.w), bfhi(q0.w),
                    bflo(q1.x), bfhi(q1.x), bflo(q1.y), bfhi(q1.y),
                    bflo(q1.z), bfhi(q1.z), bflo(q1.w), bfhi(q1.w)};
    const float* sp = a_s + h * 16;
    const float* dp = a_d + h * 16;
    float ss = 0.f, sd = 0.f;
    #pragma unroll
    for (int j = 0; j < 16; j++) {
        ss += hv[j] * sp[j];
        sd += hv[j] * dp[j];
    }
    als[i] = ss;
    ald[i] = sd;
}

// ---------------- per-edge softmax weights (unnormalized) ----------------

__global__ void k_edgew8(const int* __restrict__ col, const int* __restrict__ dstarr,
                         const float* __restrict__ als, const float* __restrict__ ald,
                         float* __restrict__ w, int Etot) {
    int i = blockIdx.x * blockDim.x + threadIdx.x;
    if (i >= Etot * 8) return;
    int j = i >> 3, h = i & 7;
    int s = col[j], d = dstarr[j];
    float e = als[s * 8 + h] + ald[d * 8 + h];
    e = LRELU(e);
    w[i] = __expf(e);
}

__global__ void k_edgew1(const int* __restrict__ col, const int* __restrict__ dstarr,
                         const float* __restrict__ als, const float* __restrict__ ald,
                         float* __restrict__ w, int Etot) {
    int j = blockIdx.x * blockDim.x + threadIdx.x;
    if (j >= Etot) return;
    float e = als[col[j]] + ald[dstarr[j]];
    e = LRELU(e);
    w[j] = __expf(e);
}

// ---------------- aggregate: 2 nodes per wave (interleaved) + fused BN stats ----------
// Per edge only ONE dependent gather (H row); col/w reads are linear.

__global__ __launch_bounds__(256) void k_agg(const int* __restrict__ rowptr,
                                             const int* __restrict__ col,
                                             const short* __restrict__ Hb,
                                             const float* __restrict__ w,
                                             const float* __restrict__ bias,
                                             float* __restrict__ out,
                                             float* __restrict__ part, int N) {
    __shared__ float red[8][128];
    int wv = threadIdx.x >> 6;
    int lane = threadIdx.x & 63;
    int nodeA = blockIdx.x * 8 + wv * 2;
    int nodeB = nodeA + 1;
    int h = lane >> 3;
    const int* Hi = (const int*)Hb;
    bool vA = nodeA < N, vB = nodeB < N;
    int jA = 0, endA = 0, jB = 0, endB = 0;
    if (vA) { jA = rowptr[nodeA]; endA = rowptr[nodeA + 1]; }
    if (vB) { jB = rowptr[nodeB]; endB = rowptr[nodeB + 1]; }
    float sA = 0.f, a0A = 0.f, a1A = 0.f;
    float sB = 0.f, a0B = 0.f, a1B = 0.f;

    // interleaved dual batches of 4 -> 8 independent H gathers in flight
    while (jA + 4 <= endA && jB + 4 <= endB) {
        int c[8];
        #pragma unroll
        for (int k = 0; k < 4; k++) { c[k] = col[jA + k]; c[4 + k] = col[jB + k]; }
        float ww[8];
        int p[8];
        #pragma unroll
        for (int k = 0; k < 4; k++) {
            ww[k] = w[(jA + k) * 8 + h];
            ww[4 + k] = w[(jB + k) * 8 + h];
            p[k] = Hi[(c[k] << 6) + lane];
            p[4 + k] = Hi[(c[4 + k] << 6) + lane];
        }
        #pragma unroll
        for (int k = 0; k < 4; k++) {
            sA += ww[k];     a0A += ww[k] * bflo(p[k]);         a1A += ww[k] * bfhi(p[k]);
            sB += ww[4 + k]; a0B += ww[4 + k] * bflo(p[4 + k]); a1B += ww[4 + k] * bfhi(p[4 + k]);
        }
        jA += 4; jB += 4;
    }
    // drain A
    for (; jA + 4 <= endA; jA += 4) {
        int c[4]; float ww[4]; int p[4];
        #pragma unroll
        for (int k = 0; k < 4; k++) c[k] = col[jA + k];
        #pragma unroll
        for (int k = 0; k < 4; k++) { ww[k] = w[(jA + k) * 8 + h]; p[k] = Hi[(c[k] << 6) + lane]; }
        #pragma unroll
        for (int k = 0; k < 4; k++) { sA += ww[k]; a0A += ww[k] * bflo(p[k]); a1A += ww[k] * bfhi(p[k]); }
    }
    for (; jA < endA; jA++) {
        int cc = col[jA];
        float wv2 = w[jA * 8 + h];
        int pp = Hi[(cc << 6) + lane];
        sA += wv2; a0A += wv2 * bflo(pp); a1A += wv2 * bfhi(pp);
    }
    // drain B
    for (; jB + 4 <= endB; jB += 4) {
        int c[4]; float ww[4]; int p[4];
        #pragma unroll
        for (int k = 0; k < 4; k++) c[k] = col[jB + k];
        #pragma unroll
        for (int k = 0; k < 4; k++) { ww[k] = w[(jB + k) * 8 + h]; p[k] = Hi[(c[k] << 6) + lane]; }
        #pragma unroll
        for (int k = 0; k < 4; k++) { sB += ww[k]; a0B += ww[k] * bflo(p[k]); a1B += ww[k] * bfhi(p[k]); }
    }
    for (; jB < endB; jB++) {
        int cc = col[jB];
        float wv2 = w[jB * 8 + h];
        int pp = Hi[(cc << 6) + lane];
        sB += wv2; a0B += wv2 * bflo(pp); a1B += wv2 * bfhi(pp);
    }

    float2 oA = make_float2(0.f, 0.f), oB = make_float2(0.f, 0.f);
    if (vA) {
        float inv = 1.f / (sA + 1e-16f);
        oA.x = a0A * inv + bias[2 * lane];
        oA.y = a1A * inv + bias[2 * lane + 1];
        ((float2*)out)[(size_t)nodeA * 64 + lane] = oA;
    }
    if (vB) {
        float inv = 1.f / (sB + 1e-16f);
        oB.x = a0B * inv + bias[2 * lane];
        oB.y = a1B * inv + bias[2 * lane + 1];
        ((float2*)out)[(size_t)nodeB * 64 + lane] = oB;
    }
    red[wv * 2][2 * lane] = oA.x;
    red[wv * 2][2 * lane + 1] = oA.y;
    red[wv * 2 + 1][2 * lane] = oB.x;
    red[wv * 2 + 1][2 * lane + 1] = oB.y;
    __syncthreads();
    if (threadIdx.x < 128) {
        int c = threadIdx.x;
        float s = 0.f, q = 0.f;
        #pragma unroll
        for (int r = 0; r < 8; r++) {
            float v = red[r][c];
            s += v;
            q += v * v;
        }
        float* slot = part + (blockIdx.x & 63) * 256;
        atomicAdd(&slot[c], s);
        atomicAdd(&slot[128 + c], q);
    }
}

// ---------------- reduce partials -> per-column (scale, shift) ----------------

__global__ __launch_bounds__(128) void k_bnreduce(const float* __restrict__ part,
                                                  const float* __restrict__ g,
                                                  const float* __restrict__ bt,
                                                  float invN, float2* __restrict__ ss) {
    int c = threadIdx.x;
    float s = 0.f, q = 0.f;
    #pragma unroll
    for (int k = 0; k < 64; k++) {
        s += part[k * 256 + c];
        q += part[k * 256 + 128 + c];
    }
    float mu = s * invN;
    float var = q * invN - mu * mu;
    float scale = rsqrtf(var + 1e-5f) * g[c];
    ss[c] = make_float2(scale, bt[c] - mu * scale);
}

// ---------------- layer-2 logits ----------------

__global__ void k_al2(const short* __restrict__ Hb2, const float* __restrict__ as2,
                      const float* __restrict__ ad2, float* __restrict__ als,
                      float* __restrict__ ald, int N) {
    int node = blockIdx.x * 4 + (threadIdx.x >> 6);
    int lc = threadIdx.x & 63;
    if (node >= N) return;
    float v = bf2f(((const unsigned short*)Hb2)[(size_t)node * 64 + lc]);
    float s = v * as2[lc];
    float d = v * ad2[lc];
    #pragma unroll
    for (int off = 32; off; off >>= 1) {
        s += __shfl_xor(s, off, 64);
        d += __shfl_xor(d, off, 64);
    }
    if (lc == 0) { als[node] = s; ald[node] = d; }
}

// ---------------- layer-2: 2 nodes per wave + aggregate + LayerNorm ----------------

__global__ __launch_bounds__(256) void k_agg2ln(const int* __restrict__ rowptr,
                                                const int* __restrict__ col,
                                                const short* __restrict__ Hb2,
                                                const float* __restrict__ w,
                                                const float* __restrict__ b2,
                                                const float* __restrict__ lng,
                                                const float* __restrict__ lnb,
                                                float* __restrict__ out, int N) {
    int wv = threadIdx.x >> 6;
    int lane = threadIdx.x & 63;
    int nodeA = blockIdx.x * 8 + wv * 2;
    int nodeB = nodeA + 1;
    const unsigned short* H = (const unsigned short*)Hb2;
    bool vA = nodeA < N, vB = nodeB < N;
    int jA = 0, endA = 0, jB = 0, endB = 0;
    if (vA) { jA = rowptr[nodeA]; endA = rowptr[nodeA + 1]; }
    if (vB) { jB = rowptr[nodeB]; endB = rowptr[nodeB + 1]; }
    float sA = 0.f, aA = 0.f, sB = 0.f, aB = 0.f;

    while (jA + 4 <= endA && jB + 4 <= endB) {
        int c[8];
        #pragma unroll
        for (int k = 0; k < 4; k++) { c[k] = col[jA + k]; c[4 + k] = col[jB + k]; }
        float ww[8];
        unsigned short p[8];
        #pragma unroll
        for (int k = 0; k < 4; k++) {
            ww[k] = w[jA + k];
            ww[4 + k] = w[jB + k];
            p[k] = H[(c[k] << 6) + lane];
            p[4 + k] = H[(c[4 + k] << 6) + lane];
        }
        #pragma unroll
        for (int k = 0; k < 4; k++) {
            sA += ww[k];     aA += ww[k] * bf2f(p[k]);
            sB += ww[4 + k]; aB += ww[4 + k] * bf2f(p[4 + k]);
        }
        jA += 4; jB += 4;
    }
    for (; jA + 4 <= endA; jA += 4) {
        int c[4]; float ww[4]; unsigned short p[4];
        #pragma unroll
        for (int k = 0; k < 4; k++) c[k] = col[jA + k];
        #pragma unroll
        for (int k = 0; k < 4; k++) { ww[k] = w[jA + k]; p[k] = H[(c[k] << 6) + lane]; }
        #pragma unroll
        for (int k = 0; k < 4; k++) { sA += ww[k]; aA += ww[k] * bf2f(p[k]); }
    }
    for (; jA < endA; jA++) {
        int cc = col[jA];
        float wv2 = w[jA];
        sA += wv2; aA += wv2 * bf2f(H[(cc << 6) + lane]);
    }
    for (; jB + 4 <= endB; jB += 4) {
        int c[4]; float ww[4]; unsigned short p[4];
        #pragma unroll
        for (int k = 0; k < 4; k++) c[k] = col[jB + k];
        #pragma unroll
        for (int k = 0; k < 4; k++) { ww[k] = w[jB + k]; p[k] = H[(c[k] << 6) + lane]; }
        #pragma unroll
        for (int k = 0; k < 4; k++) { sB += ww[k]; aB += ww[k] * bf2f(p[k]); }
    }
    for (; jB < endB; jB++) {
        int cc = col[jB];
        float wv2 = w[jB];
        sB += wv2; aB += wv2 * bf2f(H[(cc << 6) + lane]);
    }

    if (vA) {
        float v = aA / (sA + 1e-16f) + b2[lane];
        float su = v, sq = v * v;
        #pragma unroll
        for (int off = 32; off; off >>= 1) {
            su += __shfl_xor(su, off, 64);
            sq += __shfl_xor(sq, off, 64);
        }
        float mu = su * (1.f / 64.f);
        float var = sq * (1.f / 64.f) - mu * mu;
        float r = rsqrtf(var + 1e-5f);
        out[(size_t)nodeA * 64 + lane] = (v - mu) * r * lng[lane] + lnb[lane];
    }
    if (vB) {
        float v = aB / (sB + 1e-16f) + b2[lane];
        float su = v, sq = v * v;
        #pragma unroll
        for (int off = 32; off; off >>= 1) {
            su += __shfl_xor(su, off, 64);
            sq += __shfl_xor(sq, off, 64);
        }
        float mu = su * (1.f / 64.f);
        float var = sq * (1.f / 64.f) - mu * mu;
        float r = rsqrtf(var + 1e-5f);
        out[(size_t)nodeB * 64 + lane] = (v - mu) * r * lng[lane] + lnb[lane];
    }
}

// ---------------- launch ----------------

extern "C" void kernel_launch(void* const* d_in, const int* in_sizes, int n_in,
                              void* d_out, int out_size, void* d_ws, size_t ws_size,
                              hipStream_t stream) {
    const float* x   = (const float*)d_in[0];
    const int*   ei  = (const int*)d_in[1];
    const float* W0  = (const float*)d_in[2];
    const float* as0 = (const float*)d_in[3];
    const float* ad0 = (const float*)d_in[4];
    const float* b0  = (const float*)d_in[5];
    const float* g0  = (const float*)d_in[6];
    const float* bt0 = (const float*)d_in[7];
    const float* W1  = (const float*)d_in[8];
    const float* as1 = (const float*)d_in[9];
    const float* ad1 = (const float*)d_in[10];
    const float* b1  = (const float*)d_in[11];
    const float* g1  = (const float*)d_in[12];
    const float* bt1 = (const float*)d_in[13];
    const float* W2  = (const float*)d_in[14];
    const float* as2 = (const float*)d_in[15];
    const float* ad2 = (const float*)d_in[16];
    const float* b2  = (const float*)d_in[17];
    const float* lng = (const float*)d_in[18];
    const float* lnb = (const float*)d_in[19];

    const int N = in_sizes[0] / 128;
    const int E = in_sizes[1] / 2;
    const int Etot = E + N;

    char* p = (char*)d_ws;
    auto carve = [&](size_t bytes) {
        void* q = (void*)p;
        p += (bytes + 255) & ~(size_t)255;
        return q;
    };
    short* Hb     = (short*)carve((size_t)N * 128 * 2);
    float* agg    = (float*)carve((size_t)N * 128 * 4);
    float* x1     = (float*)carve((size_t)N * 128 * 4);
    float* als    = (float*)carve((size_t)N * 8 * 4);
    float* ald    = (float*)carve((size_t)N * 8 * 4);
    int*   rowptr = (int*)carve((size_t)(N + 1) * 4);
    int*   cursor = (int*)carve((size_t)(N + 1) * 4);
    int*   deg    = (int*)carve((size_t)N * 4);
    int*   col    = (int*)carve((size_t)Etot * 4);
    int*   dstarr = (int*)carve((size_t)Etot * 4);
    float* w      = (float*)carve((size_t)Etot * 8 * 4);
    float* part   = (float*)carve(64 * 256 * 4);
    float2* ss    = (float2*)carve(128 * 8);
    short* Wt0    = (short*)carve(128 * 128 * 2);
    short* Wt1    = (short*)carve(128 * 128 * 2);
    short* Wt2    = (short*)carve(64 * 128 * 2);
    int*   partial= (int*)carve(256 * 4);

    const float invN = 1.f / (float)N;
    const int eb = (E + N + 255) / 256;
    const int nsb = (N + SC - 1) / SC;

    k_wprep<<<(128 * 128 + 64 * 128 + 255) / 256, 256, 0, stream>>>(W0, W1, W2, Wt0, Wt1, Wt2);

    // CSR build
    hipMemsetAsync(deg, 0, (size_t)N * 4, stream);
    k_count<<<eb, 256, 0, stream>>>(ei + E, E, N, deg);
    k_scan1<<<nsb, 256, 0, stream>>>(deg, N, partial);
    k_scan2<<<1, 256, 0, stream>>>(partial, nsb);
    k_scan3<<<nsb, 256, 0, stream>>>(deg, N, Etot, partial, rowptr, cursor);
    k_fill<<<eb, 256, 0, stream>>>(ei, ei + E, E, N, cursor, col, dstarr);

    const int gb = (N + 127) / 128;
    const int ab = (N + 7) / 8;
    const int ewb8 = (Etot * 8 + 255) / 256;
    const int ewb1 = (Etot + 255) / 256;

    // ---- layer 0 ----
    k_gemm<128, false, false><<<gb, 256, 0, stream>>>(x, Wt0, Hb, nullptr, nullptr, nullptr, N);
    k_al<<<(N * 8 + 255) / 256, 256, 0, stream>>>(Hb, as0, ad0, als, ald, N);
    k_edgew8<<<ewb8, 256, 0, stream>>>(col, dstarr, als, ald, w, Etot);
    hipMemsetAsync(part, 0, 64 * 256 * 4, stream);
    k_agg<<<ab, 256, 0, stream>>>(rowptr, col, Hb, w, b0, agg, part, N);
    k_bnreduce<<<1, 128, 0, stream>>>(part, g0, bt0, invN, ss);

    // ---- layer 1 (BN-apply of layer 0 fused into GEMM staging) ----
    k_gemm<128, true, true><<<gb, 256, 0, stream>>>(agg, Wt1, Hb, ss, x, x1, N);
    k_al<<<(N * 8 + 255) / 256, 256, 0, stream>>>(Hb, as1, ad1, als, ald, N);
    k_edgew8<<<ewb8, 256, 0, stream>>>(col, dstarr, als, ald, w, Etot);
    hipMemsetAsync(part, 0, 64 * 256 * 4, stream);
    k_agg<<<ab, 256, 0, stream>>>(rowptr, col, Hb, w, b1, agg, part, N);
    k_bnreduce<<<1, 128, 0, stream>>>(part, g1, bt1, invN, ss);

    // ---- layer 2 (BN-apply of layer 1 fused into GEMM staging; x2 never materialized) ----
    k_gemm<64, true, false><<<gb, 256, 0, stream>>>(agg, Wt2, Hb, ss, x1, nullptr, N);
    k_al2<<<(N + 3) / 4, 256, 0, stream>>>(Hb, as2, ad2, als, ald, N);
    k_edgew1<<<ewb1, 256, 0, stream>>>(col, dstarr, als, ald, w, Etot);
    k_agg2ln<<<ab, 256, 0, stream>>>(rowptr, col, Hb, w, b2, lng, lnb, (float*)d_out, N);
}